// Round 7
// baseline (540.546 us; speedup 1.0000x reference)
//
#include <hip/hip_runtime.h>
#include <math.h>

#define NA 2048          // atoms
#define KN 24            // neighbors per atom
#define NE (NA*KN)       // edges = 49152
#define NDIM 128         // node dim
#define EDIM 64          // rbf dim
#define HDIM 256         // hidden dim
#define NLAYER 4
#define MAXDEG 256       // cap on in-degree for CSR

typedef __attribute__((ext_vector_type(8))) short bf16x8;
typedef __attribute__((ext_vector_type(4))) float f32x4;

__device__ __forceinline__ float siluf(float x) { return x / (1.0f + expf(-x)); }
__device__ __forceinline__ ushort f2b(float x) {  // RNE float->bf16
    unsigned u = __float_as_uint(x);
    return (ushort)((u + 0x7fffu + ((u >> 16) & 1u)) >> 16);
}
__device__ __forceinline__ float b2f(ushort h) { return __uint_as_float(((unsigned)h) << 16); }

// async global->LDS, 16B per lane. LDS dest = wave-uniform base + lane*16 (linear).
__device__ __forceinline__ void gl_lds(const void* g, void* lds) {
    __builtin_amdgcn_global_load_lds(
        (const __attribute__((address_space(1))) unsigned int*)g,
        (__attribute__((address_space(3))) unsigned int*)lds, 16, 0, 0);
}

struct Lat { float lx, xy, xz, ly, yz, lz; };

__device__ __forceinline__ Lat make_lattice(const float* lengths, const float* angles) {
    const float deg = 0.017453292519943295f;
    float a = lengths[0], b = lengths[1], c = lengths[2];
    float al = angles[0]*deg, be = angles[1]*deg, ga = angles[2]*deg;
    Lat L;
    L.lx = a;
    L.xy = b * cosf(ga);
    L.xz = c * cosf(be);
    L.ly = b * sinf(ga);
    L.yz = (b*c*cosf(al) - L.xy*L.xz) / L.ly;
    L.lz = sqrtf(c*c - L.xz*L.xz - L.yz*L.yz);
    return L;
}

// writes AoS cart (for coords) and SoA cx/cy/cz (for knn)
__global__ void setup_kernel(const float* __restrict__ frac, const float* __restrict__ lengths,
                             const float* __restrict__ angles, float* __restrict__ cart,
                             float* __restrict__ cxg, float* __restrict__ cyg,
                             float* __restrict__ czg, float* __restrict__ sv) {
    int i = blockIdx.x*blockDim.x + threadIdx.x;
    Lat L = make_lattice(lengths, angles);
    if (i < NA) {
        float f0 = frac[i*3], f1 = frac[i*3+1], f2 = frac[i*3+2];
        float x = f0*L.lx + f1*L.xy + f2*L.xz;
        float y = f1*L.ly + f2*L.yz;
        float z = f2*L.lz;
        cart[i*3+0] = x; cart[i*3+1] = y; cart[i*3+2] = z;
        cxg[i] = x; cyg[i] = y; czg[i] = z;
    }
    if (i < 27) {
        float s0 = (float)(i/9 - 1), s1 = (float)((i/3)%3 - 1), s2 = (float)(i%3 - 1);
        sv[i*3+0] = s0*L.lx + s1*L.xy + s2*L.xz;
        sv[i*3+1] = s1*L.ly + s2*L.yz;
        sv[i*3+2] = s2*L.lz;
    }
}

// Per-atom top-24 + fused RBF. One 64-lane wave per atom (min-image fast path).
__global__ __launch_bounds__(64) void knn_kernel(
        const float* __restrict__ cxg, const float* __restrict__ cyg,
        const float* __restrict__ czg, const float* __restrict__ lengths,
        const float* __restrict__ angles, const float* __restrict__ sv,
        int* __restrict__ dstl, ushort* __restrict__ rbf16) {
    __shared__ float sd2L[16][64];
    __shared__ int   sfL[16][64];
    const int lane = threadIdx.x;
    const int i = blockIdx.x;
    Lat L = make_lattice(lengths, angles);
    const float deg = 0.017453292519943295f;
    const bool ortho = fabsf(cosf(angles[0]*deg)) < 1e-6f &&
                       fabsf(cosf(angles[1]*deg)) < 1e-6f &&
                       fabsf(cosf(angles[2]*deg)) < 1e-6f;
    const float cx = cxg[i], cy = cyg[i], cz = czg[i];
    const float invlx = 1.0f/L.lx, invly = 1.0f/L.ly, invlz = 1.0f/L.lz;
    float R = 2.8f;
    int mycnt = 0, cnt = 0;
    bool flatm = false;
    for (int attempt = 0; attempt < 8; ++attempt) {
        const float R2 = R*R;
        mycnt = 0;
        flatm = !ortho || (attempt == 7);
        if (!flatm) {
#pragma unroll 2
            for (int j0 = 0; j0 < NA; j0 += 64) {
                const int j = j0 + lane;
                const float dx = cxg[j] - cx, dy = cyg[j] - cy, dz = czg[j] - cz;
                const float kx = rintf(dx*invlx), ky = rintf(dy*invly), kz = rintf(dz*invlz);
                const float ex = dx - (kx*L.lx + ky*L.xy + kz*L.xz);
                const float ey = dy - (ky*L.ly + kz*L.yz);
                const float ez = dz - kz*L.lz;
                const float d2 = fmaf(ex,ex,fmaf(ey,ey,ez*ez));
                if (d2 < R2 && d2 > 1e-4f) {
                    const int s = (1-(int)kx)*9 + (1-(int)ky)*3 + (1-(int)kz);
                    if (mycnt < 16) { sd2L[mycnt][lane] = d2; sfL[mycnt][lane] = (s<<11) + j; }
                    ++mycnt;
                }
            }
            if (__ballot(mycnt > 16)) {
                flatm = true;
            } else {
                int tot = mycnt;
                for (int off = 32; off > 0; off >>= 1) tot += __shfl_xor(tot, off, 64);
                cnt = tot;
            }
        }
        if (flatm) {
            cnt = 0;
            for (int s = 0; s < 27; ++s) {
                const float svx = sv[s*3], svy = sv[s*3+1], svz = sv[s*3+2];
                for (int j0 = 0; j0 < NA; j0 += 64) {
                    const int j = j0 + lane;
                    const float ex = cxg[j] + svx - cx;
                    const float ey = cyg[j] + svy - cy;
                    const float ez = czg[j] + svz - cz;
                    const float d2 = fmaf(ex,ex,fmaf(ey,ey,ez*ez));
                    const bool hit = (d2 < R2) && (d2 > 1e-4f);
                    const unsigned long long m = __ballot(hit);
                    const int rank = __popcll(m & ((1ull<<lane)-1ull));
                    const int slot = cnt + rank;
                    if (hit && slot < 1024) { sd2L[slot>>6][slot&63] = d2; sfL[slot>>6][slot&63] = (s<<11)+j; }
                    cnt += __popcll(m);
                }
            }
            cnt = min(cnt, 1024);
        }
        if (cnt >= KN) break;
        R = fminf(R*1.6f, flatm ? 8.0f : 5.9f);
    }
    int vq;
    if (flatm) vq = (lane < cnt) ? min(16, ((cnt - 1 - lane) >> 6) + 1) : 0;
    else       vq = mycnt;
    unsigned long long key[16];
#pragma unroll
    for (int q = 0; q < 16; ++q) {
        const float d2v = sd2L[q][lane];
        const int fl = sfL[q][lane];
        const unsigned long long kk = ((unsigned long long)__float_as_uint(d2v) << 20)
                                    | ((unsigned long long)(unsigned)fl << 4) | (unsigned)q;
        key[q] = (q < vq) ? kk : ~0ull;
    }
    float der[KN];
    for (int k = 0; k < KN; ++k) {
        unsigned long long lm = key[0];
#pragma unroll
        for (int q = 1; q < 16; ++q) lm = key[q] < lm ? key[q] : lm;
        for (int off = 32; off > 0; off >>= 1) {
            unsigned long long o = __shfl_xor(lm, off, 64);
            lm = o < lm ? o : lm;
        }
        der[k] = sqrtf(__uint_as_float((unsigned)(lm >> 20)));
        if (lane == 0) dstl[i*KN + k] = (int)((lm >> 4) & 2047u);
#pragma unroll
        for (int q = 0; q < 16; ++q) if (key[q] == lm) key[q] = ~0ull;
    }
    const float center = (8.0f/63.0f) * (float)lane;
    for (int k = 0; k < KN; ++k) {
        const float d = der[k];
        const float diff = d - center;
        const float g = expf(diff*diff * -32.0f);
        const float cv = 0.5f * (cosf(d * (float)(M_PI/8.0)) + 1.0f);
        rbf16[(size_t)(i*KN + k)*EDIM + lane] = f2b(g * cv);
    }
}

__global__ void scatter_kernel(const int* __restrict__ dstl, int* __restrict__ ccnt,
                               int* __restrict__ cedg) {
    int e = blockIdx.x*256 + threadIdx.x;
    if (e >= NE) return;
    int j = dstl[e];
    int slot = atomicAdd(&ccnt[j], 1);
    if (slot < MAXDEG) cedg[(size_t)j*MAXDEG + slot] = e;
}

__global__ void csort_kernel(const int* __restrict__ ccnt, int* __restrict__ cedg) {
    const int j = blockIdx.x*4 + (threadIdx.x >> 6);
    const int lane = threadIdx.x & 63;
    const int cnt = min(ccnt[j], MAXDEG);
    if (cnt <= 64) {
        int v = (lane < cnt) ? cedg[(size_t)j*MAXDEG + lane] : 0x7FFFFFFF;
#pragma unroll
        for (int k = 2; k <= 64; k <<= 1) {
#pragma unroll
            for (int s = k >> 1; s > 0; s >>= 1) {
                int o = __shfl_xor(v, s, 64);
                const bool up = ((lane & k) == 0);
                const bool lowhalf = ((lane & s) == 0);
                v = ((lowhalf == up) ? min(v, o) : max(v, o));
            }
        }
        if (lane < cnt) cedg[(size_t)j*MAXDEG + lane] = v;
    } else if (lane == 0) {
        int* L = cedg + (size_t)j*MAXDEG;
        for (int a = 1; a < cnt; ++a) {
            int v = L[a]; int b = a - 1;
            while (b >= 0 && L[b] > v) { L[b+1] = L[b]; --b; }
            L[b+1] = v;
        }
    }
}

__global__ void nf_init_kernel(const int* __restrict__ atom_types, const float* __restrict__ ts,
                               const float* __restrict__ emb, const float* __restrict__ tW,
                               const float* __restrict__ tb, float* __restrict__ nf,
                               ushort* __restrict__ nf16) {
    int i = blockIdx.x, c = threadIdx.x;  // 128 threads
    float acc = emb[atom_types[i]*NDIM + c] + tb[c];
    for (int kk = 0; kk < 128; ++kk) acc += ts[i*128 + kk] * tW[kk*NDIM + c];
    nf[i*NDIM + c] = acc;
    nf16[i*NDIM + c] = f2b(acc);
}

// LDS-tiled transpose+convert to Bt layouts. eW1 is split:
//   rows 0..127 -> eW1abt cols 0..255 (src part), rows 128..255 -> eW1abt rows 256..511,
//   rows 256..319 -> eW1ct [256][64].
// blocks: eW1 80 | eW2 64 | cW1 32 | nW1 96 | nW2 32 -> 304
__global__ void wprep_all(const float* __restrict__ eW1, const float* __restrict__ eW2,
                          const float* __restrict__ cW1, const float* __restrict__ nW1,
                          const float* __restrict__ nW2,
                          ushort* __restrict__ eW1abt, ushort* __restrict__ eW1ct,
                          ushort* __restrict__ eW2t, ushort* __restrict__ cW1t,
                          ushort* __restrict__ nW1t, ushort* __restrict__ nW2t) {
    __shared__ float tile[64][65];
    const int b = blockIdx.x;
    int l, kt, nt, Kk, Nn, Kd, n0d, k0d;
    const float* Wl; ushort* Wd;
    if (b < 80) {
        int rel = b; l = rel/20; int r = rel%20; kt = r/4; nt = r%4;
        Kk = 320; Nn = 256; Wl = eW1 + (size_t)l*Kk*Nn;
        if (kt < 2)      { Wd = eW1abt + (size_t)l*512*128; Kd = 128; n0d = nt*64;       k0d = kt*64; }
        else if (kt < 4) { Wd = eW1abt + (size_t)l*512*128; Kd = 128; n0d = nt*64 + 256; k0d = (kt-2)*64; }
        else             { Wd = eW1ct  + (size_t)l*256*64;  Kd = 64;  n0d = nt*64;       k0d = 0; }
    } else if (b < 144) {
        int rel = b-80; l = rel/16; int r = rel%16; kt = r/4; nt = r%4;
        Kk = 256; Nn = 256; Wl = eW2 + (size_t)l*Kk*Nn; Wd = eW2t + (size_t)l*Kk*Nn;
        Kd = 256; n0d = nt*64; k0d = kt*64;
    } else if (b < 176) {
        int rel = b-144; l = rel/8; int r = rel%8; kt = r/2; nt = r%2;
        Kk = 256; Nn = 128; Wl = cW1 + (size_t)l*Kk*Nn; Wd = cW1t + (size_t)l*Kk*Nn;
        Kd = 256; n0d = nt*64; k0d = kt*64;
    } else if (b < 272) {
        int rel = b-176; l = rel/24; int r = rel%24; kt = r/4; nt = r%4;
        Kk = 384; Nn = 256; Wl = nW1 + (size_t)l*Kk*Nn; Wd = nW1t + (size_t)l*Kk*Nn;
        Kd = 384; n0d = nt*64; k0d = kt*64;
    } else {
        int rel = b-272; l = rel/8; int r = rel%8; kt = r/2; nt = r%2;
        Kk = 256; Nn = 128; Wl = nW2 + (size_t)l*Kk*Nn; Wd = nW2t + (size_t)l*Kk*Nn;
        Kd = 256; n0d = nt*64; k0d = kt*64;
    }
    const int k0 = kt*64, n0 = nt*64;
    const int tr = threadIdx.x >> 6, tc = threadIdx.x & 63;
#pragma unroll
    for (int q = 0; q < 16; ++q) {
        const int k = q*4 + tr;
        tile[k][tc] = Wl[(size_t)(k0 + k)*Nn + n0 + tc];
    }
    __syncthreads();
#pragma unroll
    for (int q = 0; q < 16; ++q) {
        const int n = q*4 + tr;
        Wd[(size_t)(n0d + n)*Kd + k0d + tc] = f2b(tile[tc][n]);
    }
}

// bf16 MFMA GEMM, 128x128 tile, BK=32, counted-vmcnt double buffer.
// AMODE: 0 dense A | 2 ncat [nf16|aggr16]
// EPI: 0 bias+silu -> bf16 | 1 raw -> bf16 (no bias) | 2 bias+res(fp32) -> fp32 Cf AND bf16 C16
template<int AMODE, int EPI>
__global__ __launch_bounds__(256) void bgemm_kernel(
        const ushort* __restrict__ A, const ushort* __restrict__ nf16,
        const ushort* __restrict__ aggr16, const ushort* __restrict__ Bt,
        const float* __restrict__ bias, const float* __restrict__ res,
        float* __restrict__ Cf, ushort* __restrict__ C16, int M, int Nn, int Kk) {
    __shared__ alignas(16) ushort As[2][128*32];
    __shared__ alignas(16) ushort Bs[2][128*32];
    const int t = threadIdx.x;
    const int wave = t >> 6, lane = t & 63;
    const int row0 = blockIdx.x*128, col0 = blockIdx.y*128;
    const int wr = (wave >> 1)*64, wc = (wave & 1)*64;
    const int lr = lane & 15, g0 = lane >> 4;

    auto STAGE = [&](int buf, int k0) {
#pragma unroll
        for (int q = 0; q < 4; ++q) {
            const int rbase = (q & 1)*64 + wave*16;
            const int r = rbase + (lane >> 2);
            const int g = (lane & 3) ^ ((r >> 1) & 3);
            const int kg = k0 + g*8;
            const int ldsbase = rbase * 32;
            if (q < 2) {
                const ushort* gp;
                if (AMODE == 0) {
                    gp = A + (size_t)(row0 + r)*Kk + kg;
                } else {
                    const int e = row0 + r;
                    if (kg < NDIM) gp = nf16 + (size_t)e*NDIM + kg;
                    else           gp = aggr16 + (size_t)e*HDIM + (kg - NDIM);
                }
                gl_lds(gp, &As[buf][ldsbase]);
            } else {
                gl_lds(Bt + (size_t)(col0 + r)*Kk + kg, &Bs[buf][ldsbase]);
            }
        }
    };

    f32x4 acc[4][4] = {};
    const int nk = Kk >> 5;
    STAGE(0, 0);
    int cur = 0;
    for (int it = 0; it < nk; ++it) {
        if (it + 1 < nk) {
            STAGE(cur ^ 1, (it + 1) << 5);
            asm volatile("s_waitcnt vmcnt(4)" ::: "memory");
        } else {
            asm volatile("s_waitcnt vmcnt(0)" ::: "memory");
        }
        __builtin_amdgcn_sched_barrier(0);
        __builtin_amdgcn_s_barrier();
        __builtin_amdgcn_sched_barrier(0);
        bf16x8 af[4], bfr[4];
#pragma unroll
        for (int m = 0; m < 4; ++m) {
            const int rA = wr + m*16 + lr;
            af[m] = *reinterpret_cast<const bf16x8*>(&As[cur][rA*32 + (g0 ^ ((rA>>1)&3))*8]);
        }
#pragma unroll
        for (int n = 0; n < 4; ++n) {
            const int rB = wc + n*16 + lr;
            bfr[n] = *reinterpret_cast<const bf16x8*>(&Bs[cur][rB*32 + (g0 ^ ((rB>>1)&3))*8]);
        }
#pragma unroll
        for (int m = 0; m < 4; ++m)
#pragma unroll
            for (int n = 0; n < 4; ++n)
                acc[m][n] = __builtin_amdgcn_mfma_f32_16x16x32_bf16(af[m], bfr[n], acc[m][n], 0, 0, 0);
        asm volatile("s_waitcnt lgkmcnt(0)" ::: "memory");
        __builtin_amdgcn_sched_barrier(0);
        __builtin_amdgcn_s_barrier();
        __builtin_amdgcn_sched_barrier(0);
        cur ^= 1;
    }

#pragma unroll
    for (int n = 0; n < 4; ++n) {
        const int cc = col0 + wc + n*16 + lr;
        const float bb = (EPI == 1) ? 0.0f : bias[cc];
#pragma unroll
        for (int m = 0; m < 4; ++m) {
#pragma unroll
            for (int j = 0; j < 4; ++j) {
                const int rr = row0 + wr + m*16 + (lane >> 4)*4 + j;
                float x = acc[m][n][j] + bb;
                if constexpr (EPI == 0) {
                    C16[(size_t)rr*Nn + cc] = f2b(siluf(x));
                } else if constexpr (EPI == 1) {
                    C16[(size_t)rr*Nn + cc] = f2b(x);
                } else {
                    x += res[(size_t)rr*Nn + cc];
                    Cf[(size_t)rr*Nn + cc] = x;
                    C16[(size_t)rr*Nn + cc] = f2b(x);
                }
            }
        }
    }
}

// Fused per-layer edge kernel: 128 edges/block, 256 threads (4 waves, 2x2).
// Stage A: h1 = silu(P_src[src] + P_dst[dst] + rbf@W1c + eb1)   (K=64 MFMA + gathers)
// Stage B: msg = silu(h1 @ eW2^T + eb2)                          (K=256, LDS A-operand)
// Stage C: wv  = silu(msg @ cW1^T + cb1) . cW2 + cb2             (K=256, LDS A-operand)
// h1/msg live in one 64KB LDS tile (in-place, per-thread element ownership).
// LDS element (r,c) at byte r*512 + ((c>>3) ^ ((r&7)<<2))*16 + (c&7)*2 (bank swizzle).
__global__ __launch_bounds__(256) void edge_kernel(
        const ushort* __restrict__ P16,      // [2048][512]: cols 0..255 src-part, 256..511 dst-part
        const int* __restrict__ dstl,
        const ushort* __restrict__ rbf16,    // [NE][64]
        const ushort* __restrict__ W1ct,     // [256][64]
        const ushort* __restrict__ W2t,      // [256][256]
        const ushort* __restrict__ cW1t,     // [128][256]
        const float* __restrict__ eb1, const float* __restrict__ eb2,
        const float* __restrict__ cb1, const float* __restrict__ cW2v,
        const float* __restrict__ cb2v,
        ushort* __restrict__ msg16, float* __restrict__ wvout) {
    __shared__ alignas(16) ushort Hs[128*256];   // Pdst -> h1 -> msg
    __shared__ alignas(16) ushort Ps[8*272];     // src-part rows (<=7 distinct), padded stride
    __shared__ alignas(16) char U[49152];        // union: {Rb 16K | Wc 32K} -> {Bs 32K | Cs 16K}
    __shared__ int sdst[128];
    __shared__ float wred[2][128];
    ushort* Rb = (ushort*)U;                     // [128][64]
    ushort* Wc = (ushort*)(U + 16384);           // [256][64]
    ushort* Bs = (ushort*)U;                     // 2 x [256][32]
    ushort* Cs = (ushort*)(U + 32768);           // 2 x [128][32]

    const int t = threadIdx.x, wave = t >> 6, lane = t & 63;
    const int row0 = blockIdx.x*128;
    const int src0 = row0 / KN;
    if (t < 128) sdst[t] = dstl[row0 + t];
    __syncthreads();

    const int wr = (wave >> 1)*64;
    const int wcB = (wave & 1)*128;              // stage A/B column half
    const int lr = lane & 15, g0 = lane >> 4;

    // ---- Stage A loads ----
    // P_dst gather -> Hs (swizzled source chunks, linear LDS dest)
#pragma unroll
    for (int q = 0; q < 16; ++q) {
        const int base = wave*16384 + q*1024;            // bytes
        const int r = (base >> 9) + (lane >> 5);         // row (2 rows per issue)
        const int cp = lane & 31;                        // LDS chunk
        const int g = cp ^ ((r & 7) << 2);               // global chunk
        gl_lds(P16 + (size_t)sdst[r]*512 + 256 + g*8, (char*)Hs + base);
    }
    // rbf tile -> Rb (8 chunks/row, swizzle g ^ (r&7))
#pragma unroll
    for (int q = 0; q < 4; ++q) {
        const int base = wave*4096 + q*1024;
        const int r = (base >> 7) + (lane >> 3);
        const int g = (lane & 7) ^ (r & 7);
        gl_lds(rbf16 + (size_t)(row0 + r)*64 + g*8, (char*)Rb + base);
    }
    // W1c^T -> Wc
#pragma unroll
    for (int q = 0; q < 8; ++q) {
        const int base = wave*8192 + q*1024;
        const int n = (base >> 7) + (lane >> 3);
        const int g = (lane & 7) ^ (n & 7);
        gl_lds(W1ct + (size_t)n*64 + g*8, (char*)Wc + base);
    }
    // P_src rows (8 rows x 256 cols) -> Ps, padded stride 272
    {
        const int rid = t >> 5, cp = t & 31;
        const int srow = min(src0 + rid, NA - 1);
        uint4 v = *reinterpret_cast<const uint4*>(P16 + (size_t)srow*512 + cp*8);
        *reinterpret_cast<uint4*>(&Ps[rid*272 + cp*8]) = v;
    }
    __syncthreads();

    // ---- Stage A MFMA: rbf @ W1c (K=64) ----
    f32x4 acc[4][8];
#pragma unroll
    for (int m = 0; m < 4; ++m)
#pragma unroll
        for (int n = 0; n < 8; ++n) acc[m][n] = (f32x4){0.f,0.f,0.f,0.f};
#pragma unroll
    for (int ks = 0; ks < 2; ++ks) {
        bf16x8 af[4], bfr[8];
#pragma unroll
        for (int m = 0; m < 4; ++m) {
            const int rA = wr + m*16 + lr;
            af[m] = *reinterpret_cast<const bf16x8*>(&Rb[rA*64 + ((ks*4 + g0) ^ (rA & 7))*8]);
        }
#pragma unroll
        for (int n = 0; n < 8; ++n) {
            const int rB = wcB + n*16 + lr;
            bfr[n] = *reinterpret_cast<const bf16x8*>(&Wc[rB*64 + ((ks*4 + g0) ^ (rB & 7))*8]);
        }
#pragma unroll
        for (int m = 0; m < 4; ++m)
#pragma unroll
            for (int n = 0; n < 8; ++n)
                acc[m][n] = __builtin_amdgcn_mfma_f32_16x16x32_bf16(af[m], bfr[n], acc[m][n], 0, 0, 0);
    }
    // ---- Stage A epilogue: h1 in-place into Hs ----
#pragma unroll
    for (int n = 0; n < 8; ++n) {
        const int cc = wcB + n*16 + lr;
        const float b1 = eb1[cc];
#pragma unroll
        for (int m = 0; m < 4; ++m) {
#pragma unroll
            for (int j = 0; j < 4; ++j) {
                const int rr = wr + m*16 + g0*4 + j;
                const int srel = (row0 + rr)/KN - src0;
                const float ps = b2f(Ps[srel*272 + cc]);
                const int hoff = rr*256 + (((cc>>3) ^ ((rr&7)<<2))*8) + (cc&7);
                const float pd = b2f(Hs[hoff]);
                Hs[hoff] = f2b(siluf(acc[m][n][j] + ps + pd + b1));
            }
        }
    }
    __syncthreads();

    // ---- Stage B: msg = silu(h1 @ W2^T + eb2), K=256 ----
#pragma unroll
    for (int m = 0; m < 4; ++m)
#pragma unroll
        for (int n = 0; n < 8; ++n) acc[m][n] = (f32x4){0.f,0.f,0.f,0.f};
    auto STAGEB = [&](int buf, int k0) {
#pragma unroll
        for (int q = 0; q < 4; ++q) {
            const int loc = wave*4096 + q*1024;          // bytes within buffer
            const int n = (loc >> 6) + (lane >> 2);      // row (64B rows)
            const int g = (lane & 3) ^ ((n >> 1) & 3);
            gl_lds(W2t + (size_t)n*256 + k0 + g*8, (char*)Bs + buf*16384 + loc);
        }
    };
    int cur = 0;
    STAGEB(0, 0);
    for (int it = 0; it < 8; ++it) {
        if (it + 1 < 8) {
            STAGEB(cur ^ 1, (it + 1)*32);
            asm volatile("s_waitcnt vmcnt(4)" ::: "memory");
        } else {
            asm volatile("s_waitcnt vmcnt(0)" ::: "memory");
        }
        __builtin_amdgcn_sched_barrier(0);
        __builtin_amdgcn_s_barrier();
        __builtin_amdgcn_sched_barrier(0);
        bf16x8 af[4], bfr[8];
#pragma unroll
        for (int m = 0; m < 4; ++m) {
            const int rA = wr + m*16 + lr;
            af[m] = *reinterpret_cast<const bf16x8*>(&Hs[rA*256 + (((it*4 + g0) ^ ((rA&7)<<2))*8)]);
        }
#pragma unroll
        for (int n = 0; n < 8; ++n) {
            const int rB = wcB + n*16 + lr;
            bfr[n] = *reinterpret_cast<const bf16x8*>(&Bs[(size_t)cur*8192 + rB*32 + (g0 ^ ((rB>>1)&3))*8]);
        }
#pragma unroll
        for (int m = 0; m < 4; ++m)
#pragma unroll
            for (int n = 0; n < 8; ++n)
                acc[m][n] = __builtin_amdgcn_mfma_f32_16x16x32_bf16(af[m], bfr[n], acc[m][n], 0, 0, 0);
        asm volatile("s_waitcnt lgkmcnt(0)" ::: "memory");
        __builtin_amdgcn_sched_barrier(0);
        __builtin_amdgcn_s_barrier();
        __builtin_amdgcn_sched_barrier(0);
        cur ^= 1;
    }
    // ---- Stage B epilogue: msg in-place into Hs ----
#pragma unroll
    for (int n = 0; n < 8; ++n) {
        const int cc = wcB + n*16 + lr;
        const float b2 = eb2[cc];
#pragma unroll
        for (int m = 0; m < 4; ++m) {
#pragma unroll
            for (int j = 0; j < 4; ++j) {
                const int rr = wr + m*16 + g0*4 + j;
                const int hoff = rr*256 + (((cc>>3) ^ ((rr&7)<<2))*8) + (cc&7);
                Hs[hoff] = f2b(siluf(acc[m][n][j] + b2));
            }
        }
    }
    __syncthreads();
    // coalesced global store of msg (unswizzle on the fly)
#pragma unroll
    for (int q = 0; q < 16; ++q) {
        const int off = wave*16384 + q*1024 + lane*16;   // bytes, LDS-linear
        const int r = off >> 9;
        const int cp = (off >> 4) & 31;
        const int g = cp ^ ((r & 7) << 2);
        uint4 v = *reinterpret_cast<const uint4*>((const char*)Hs + off);
        *reinterpret_cast<uint4*>(msg16 + (size_t)(row0 + r)*256 + g*8) = v;
    }

    // ---- Stage C: wv = silu(msg @ cW1^T + cb1) . cW2 + cb2, K=256 ----
    const int wcC = (wave & 1)*64;
    f32x4 acc3[4][4];
#pragma unroll
    for (int m = 0; m < 4; ++m)
#pragma unroll
        for (int n = 0; n < 4; ++n) acc3[m][n] = (f32x4){0.f,0.f,0.f,0.f};
    auto STAGEC = [&](int buf, int k0) {
#pragma unroll
        for (int q = 0; q < 2; ++q) {
            const int loc = wave*2048 + q*1024;
            const int n = (loc >> 6) + (lane >> 2);
            const int g = (lane & 3) ^ ((n >> 1) & 3);
            gl_lds(cW1t + (size_t)n*256 + k0 + g*8, (char*)Cs + buf*8192 + loc);
        }
    };
    cur = 0;
    STAGEC(0, 0);
    for (int it = 0; it < 8; ++it) {
        if (it + 1 < 8) {
            STAGEC(cur ^ 1, (it + 1)*32);
            asm volatile("s_waitcnt vmcnt(2)" ::: "memory");
        } else {
            asm volatile("s_waitcnt vmcnt(0)" ::: "memory");
        }
        __builtin_amdgcn_sched_barrier(0);
        __builtin_amdgcn_s_barrier();
        __builtin_amdgcn_sched_barrier(0);
        bf16x8 af[4], bfr[4];
#pragma unroll
        for (int m = 0; m < 4; ++m) {
            const int rA = wr + m*16 + lr;
            af[m] = *reinterpret_cast<const bf16x8*>(&Hs[rA*256 + (((it*4 + g0) ^ ((rA&7)<<2))*8)]);
        }
#pragma unroll
        for (int n = 0; n < 4; ++n) {
            const int rB = wcC + n*16 + lr;
            bfr[n] = *reinterpret_cast<const bf16x8*>(&Cs[(size_t)cur*4096 + rB*32 + (g0 ^ ((rB>>1)&3))*8]);
        }
#pragma unroll
        for (int m = 0; m < 4; ++m)
#pragma unroll
            for (int n = 0; n < 4; ++n)
                acc3[m][n] = __builtin_amdgcn_mfma_f32_16x16x32_bf16(af[m], bfr[n], acc3[m][n], 0, 0, 0);
        asm volatile("s_waitcnt lgkmcnt(0)" ::: "memory");
        __builtin_amdgcn_sched_barrier(0);
        __builtin_amdgcn_s_barrier();
        __builtin_amdgcn_sched_barrier(0);
        cur ^= 1;
    }
    float part[4][4];
#pragma unroll
    for (int m = 0; m < 4; ++m)
#pragma unroll
        for (int j = 0; j < 4; ++j) part[m][j] = 0.0f;
#pragma unroll
    for (int n = 0; n < 4; ++n) {
        const int cc = wcC + n*16 + lr;
        const float bb = cb1[cc];
        const float cw = cW2v[cc];
#pragma unroll
        for (int m = 0; m < 4; ++m)
#pragma unroll
            for (int j = 0; j < 4; ++j)
                part[m][j] += siluf(acc3[m][n][j] + bb) * cw;
    }
#pragma unroll
    for (int off = 1; off < 16; off <<= 1)
#pragma unroll
        for (int m = 0; m < 4; ++m)
#pragma unroll
            for (int j = 0; j < 4; ++j)
                part[m][j] += __shfl_xor(part[m][j], off, 64);
    if (lr == 0) {
#pragma unroll
        for (int m = 0; m < 4; ++m)
#pragma unroll
            for (int j = 0; j < 4; ++j)
                wred[wave & 1][wr + m*16 + g0*4 + j] = part[m][j];
    }
    __syncthreads();
    if (t < 128) wvout[row0 + t] = wred[0][t] + wred[1][t] + cb2v[0];
}

// aggr16[j,:] = bf16( sum over incoming edges of msg[e,:] ), one wave per node
__global__ void aggr_kernel(const ushort* __restrict__ msg16, const int* __restrict__ ccnt,
                            const int* __restrict__ cedg, ushort* __restrict__ aggr16) {
    __shared__ int se[4][64];
    const int w = threadIdx.x >> 6, lane = threadIdx.x & 63;
    const int j = blockIdx.x*4 + w;
    const int cnt = min(ccnt[j], MAXDEG);
    se[w][lane] = (lane < cnt) ? cedg[(size_t)j*MAXDEG + lane] : 0;
    __syncthreads();
    const int c4 = lane*4;
    float s0 = 0, s1 = 0, s2 = 0, s3 = 0;
    const int lim = min(cnt, 64);
    for (int q = 0; q < lim; ++q) {
        const int e = se[w][q];
        ushort4 v = *reinterpret_cast<const ushort4*>(&msg16[(size_t)e*HDIM + c4]);
        s0 += b2f(v.x); s1 += b2f(v.y); s2 += b2f(v.z); s3 += b2f(v.w);
    }
    for (int q = 64; q < cnt; ++q) {
        const int e = cedg[(size_t)j*MAXDEG + q];
        ushort4 v = *reinterpret_cast<const ushort4*>(&msg16[(size_t)e*HDIM + c4]);
        s0 += b2f(v.x); s1 += b2f(v.y); s2 += b2f(v.z); s3 += b2f(v.w);
    }
    ushort4 o; o.x = f2b(s0); o.y = f2b(s1); o.z = f2b(s2); o.w = f2b(s3);
    *reinterpret_cast<ushort4*>(&aggr16[(size_t)j*HDIM + c4]) = o;
}

// coords update: one wave per node, lanes parallel over edges
__global__ void coords_kernel(const float* __restrict__ cold, const float* __restrict__ wv,
                              const int* __restrict__ ccnt, const int* __restrict__ cedg,
                              float* __restrict__ cnew) {
    const int w = threadIdx.x >> 6, lane = threadIdx.x & 63;
    const int j = blockIdx.x*4 + w;
    const int cnt = min(ccnt[j], MAXDEG);
    const float jx = cold[j*3], jy = cold[j*3+1], jz = cold[j*3+2];
    float dx = 0, dy = 0, dz = 0;
    for (int q = lane; q < cnt; q += 64) {
        const int e = cedg[(size_t)j*MAXDEG + q];
        const int si = e / KN;
        const float ax = cold[si*3]   - jx;
        const float ay = cold[si*3+1] - jy;
        const float az = cold[si*3+2] - jz;
        const float inv = wv[e] / (sqrtf(ax*ax + ay*ay + az*az) + 1e-8f);
        dx += inv*ax; dy += inv*ay; dz += inv*az;
    }
    for (int off = 32; off > 0; off >>= 1) {
        dx += __shfl_xor(dx, off, 64);
        dy += __shfl_xor(dy, off, 64);
        dz += __shfl_xor(dz, off, 64);
    }
    if (lane == 0) {
        cnew[j*3]   = jx + dx;
        cnew[j*3+1] = jy + dy;
        cnew[j*3+2] = jz + dz;
    }
}

__global__ void copyout_kernel(const float* __restrict__ nf, const float* __restrict__ coords,
                               float* __restrict__ out) {
    int idx = blockIdx.x*256 + threadIdx.x;
    if (idx < NA*NDIM) out[idx] = nf[idx];
    else if (idx < NA*NDIM + NA*3) out[idx] = coords[idx - NA*NDIM];
}

extern "C" void kernel_launch(void* const* d_in, const int* in_sizes, int n_in,
                              void* d_out, int out_size, void* d_ws, size_t ws_size,
                              hipStream_t stream) {
    const int*   atom_types = (const int*)  d_in[0];
    const float* frac       = (const float*)d_in[1];
    const float* lengths    = (const float*)d_in[2];
    const float* angles     = (const float*)d_in[3];
    const float* timesteps  = (const float*)d_in[4];
    const float* emb        = (const float*)d_in[5];
    const float* tW         = (const float*)d_in[6];
    const float* tb         = (const float*)d_in[7];
    const float* eW1        = (const float*)d_in[8];
    const float* eb1        = (const float*)d_in[9];
    const float* eW2        = (const float*)d_in[10];
    const float* eb2        = (const float*)d_in[11];
    const float* nW1        = (const float*)d_in[12];
    const float* nb1        = (const float*)d_in[13];
    const float* nW2        = (const float*)d_in[14];
    const float* nb2        = (const float*)d_in[15];
    const float* cW1        = (const float*)d_in[16];
    const float* cb1        = (const float*)d_in[17];
    const float* cW2        = (const float*)d_in[18];
    const float* cb2        = (const float*)d_in[19];

    char* p = (char*)d_ws;
    auto alloc = [&](size_t bytes) { char* q = p; p += (bytes + 255) & ~(size_t)255; return q; };
    float*  sv    = (float*) alloc(81*4);
    float*  c0    = (float*) alloc((size_t)NA*3*4);
    float*  c1    = (float*) alloc((size_t)NA*3*4);
    float*  cxg   = (float*) alloc((size_t)NA*4);
    float*  cyg   = (float*) alloc((size_t)NA*4);
    float*  czg   = (float*) alloc((size_t)NA*4);
    float*  nf    = (float*) alloc((size_t)NA*NDIM*4);
    int*    dstl  = (int*)   alloc((size_t)NE*4);
    ushort* rbf16 = (ushort*)alloc((size_t)NE*EDIM*2);
    int*    ccnt  = (int*)   alloc((size_t)NA*4);
    int*    cedg  = (int*)   alloc((size_t)NA*MAXDEG*4);
    ushort* aggr16= (ushort*)alloc((size_t)NA*HDIM*2);
    ushort* t116  = (ushort*)alloc((size_t)NA*HDIM*2);
    float*  wv    = (float*) alloc((size_t)NE*4);
    ushort* nf16  = (ushort*)alloc((size_t)NA*NDIM*2);
    ushort* P16   = (ushort*)alloc((size_t)NA*512*2);
    ushort* msg16 = (ushort*)alloc((size_t)NE*HDIM*2);
    ushort* eW1abt= (ushort*)alloc((size_t)NLAYER*512*128*2);
    ushort* eW1ct = (ushort*)alloc((size_t)NLAYER*256*64*2);
    ushort* eW2t  = (ushort*)alloc((size_t)NLAYER*HDIM*HDIM*2);
    ushort* cW1t  = (ushort*)alloc((size_t)NLAYER*(HDIM/2)*HDIM*2);
    ushort* nW1t  = (ushort*)alloc((size_t)NLAYER*(NDIM+HDIM)*HDIM*2);
    ushort* nW2t  = (ushort*)alloc((size_t)NLAYER*HDIM*NDIM*2);

    setup_kernel<<<8, 256, 0, stream>>>(frac, lengths, angles, c0, cxg, cyg, czg, sv);
    knn_kernel<<<NA, 64, 0, stream>>>(cxg, cyg, czg, lengths, angles, sv, dstl, rbf16);
    hipMemsetAsync(ccnt, 0, (size_t)NA*4, stream);
    scatter_kernel<<<NE/256, 256, 0, stream>>>(dstl, ccnt, cedg);
    csort_kernel<<<NA/4, 256, 0, stream>>>(ccnt, cedg);
    nf_init_kernel<<<NA, 128, 0, stream>>>(atom_types, timesteps, emb, tW, tb, nf, nf16);
    wprep_all<<<304, 256, 0, stream>>>(eW1, eW2, cW1, nW1, nW2,
                                       eW1abt, eW1ct, eW2t, cW1t, nW1t, nW2t);

    float* cin = c0; float* cout = c1;
    for (int l = 0; l < NLAYER; ++l) {
        const float* eb1l = eb1 + (size_t)l*HDIM;
        const float* eb2l = eb2 + (size_t)l*HDIM;
        const float* nb1l = nb1 + (size_t)l*HDIM;
        const float* nb2l = nb2 + (size_t)l*NDIM;
        const float* cb1l = cb1 + (size_t)l*(HDIM/2);
        const float* cW2l = cW2 + (size_t)l*(HDIM/2);
        const float* cb2l = cb2 + (size_t)l;

        // P = nf16 @ [W1a|W1b]  (2048x512, no bias/act)
        bgemm_kernel<0,1><<<dim3(16, 4), 256, 0, stream>>>(
            nf16, nullptr, nullptr, eW1abt + (size_t)l*512*128, nullptr, nullptr,
            nullptr, P16, NA, 512, 128);
        // fused edge pipeline: h1 -> msg -> wv
        edge_kernel<<<NE/128, 256, 0, stream>>>(
            P16, dstl, rbf16, eW1ct + (size_t)l*256*64, eW2t + (size_t)l*HDIM*HDIM,
            cW1t + (size_t)l*(HDIM/2)*HDIM, eb1l, eb2l, cb1l, cW2l, cb2l, msg16, wv);
        // aggr = segment_sum(msg, dst)
        aggr_kernel<<<NA/4, 256, 0, stream>>>(msg16, ccnt, cedg, aggr16);
        // t1 = silu([nf|aggr] @ nW1 + nb1)
        bgemm_kernel<2,0><<<dim3(NA/128, HDIM/128), 256, 0, stream>>>(
            nullptr, nf16, aggr16, nW1t + (size_t)l*(NDIM+HDIM)*HDIM, nb1l, nullptr,
            nullptr, t116, NA, HDIM, NDIM+HDIM);
        // nf = nf + t1 @ nW2 + nb2
        bgemm_kernel<0,2><<<dim3(NA/128, NDIM/128), 256, 0, stream>>>(
            t116, nullptr, nullptr, nW2t + (size_t)l*HDIM*NDIM, nb2l, nf,
            nf, nf16, NA, NDIM, HDIM);
        // coords update
        coords_kernel<<<NA/4, 256, 0, stream>>>(cin, wv, ccnt, cedg, cout);
        float* tmp = cin; cin = cout; cout = tmp;
    }
    copyout_kernel<<<(NA*NDIM + NA*3)/256, 256, 0, stream>>>(nf, cin, (float*)d_out);
}

// Round 8
// 455.675 us; speedup vs baseline: 1.1863x; 1.1863x over previous
//
#include <hip/hip_runtime.h>
#include <math.h>

#define NA 2048          // atoms
#define KN 24            // neighbors per atom
#define NE (NA*KN)       // edges = 49152
#define NDIM 128         // node dim
#define EDIM 64          // rbf dim
#define HDIM 256         // hidden dim
#define NLAYER 4
#define MAXDEG 256       // cap on in-degree for CSR

typedef __attribute__((ext_vector_type(8))) short bf16x8;
typedef __attribute__((ext_vector_type(4))) float f32x4;

__device__ __forceinline__ float siluf(float x) { return x / (1.0f + expf(-x)); }
__device__ __forceinline__ ushort f2b(float x) {  // RNE float->bf16
    unsigned u = __float_as_uint(x);
    return (ushort)((u + 0x7fffu + ((u >> 16) & 1u)) >> 16);
}
__device__ __forceinline__ float b2f(ushort h) { return __uint_as_float(((unsigned)h) << 16); }

// async global->LDS, 16B per lane. LDS dest = wave-uniform base + lane*16 (linear).
__device__ __forceinline__ void gl_lds(const void* g, void* lds) {
    __builtin_amdgcn_global_load_lds(
        (const __attribute__((address_space(1))) unsigned int*)g,
        (__attribute__((address_space(3))) unsigned int*)lds, 16, 0, 0);
}

struct Lat { float lx, xy, xz, ly, yz, lz; };

__device__ __forceinline__ Lat make_lattice(const float* lengths, const float* angles) {
    const float deg = 0.017453292519943295f;
    float a = lengths[0], b = lengths[1], c = lengths[2];
    float al = angles[0]*deg, be = angles[1]*deg, ga = angles[2]*deg;
    Lat L;
    L.lx = a;
    L.xy = b * cosf(ga);
    L.xz = c * cosf(be);
    L.ly = b * sinf(ga);
    L.yz = (b*c*cosf(al) - L.xy*L.xz) / L.ly;
    L.lz = sqrtf(c*c - L.xz*L.xz - L.yz*L.yz);
    return L;
}

// writes AoS cart (for coords) and SoA cx/cy/cz (for knn)
__global__ void setup_kernel(const float* __restrict__ frac, const float* __restrict__ lengths,
                             const float* __restrict__ angles, float* __restrict__ cart,
                             float* __restrict__ cxg, float* __restrict__ cyg,
                             float* __restrict__ czg, float* __restrict__ sv) {
    int i = blockIdx.x*blockDim.x + threadIdx.x;
    Lat L = make_lattice(lengths, angles);
    if (i < NA) {
        float f0 = frac[i*3], f1 = frac[i*3+1], f2 = frac[i*3+2];
        float x = f0*L.lx + f1*L.xy + f2*L.xz;
        float y = f1*L.ly + f2*L.yz;
        float z = f2*L.lz;
        cart[i*3+0] = x; cart[i*3+1] = y; cart[i*3+2] = z;
        cxg[i] = x; cyg[i] = y; czg[i] = z;
    }
    if (i < 27) {
        float s0 = (float)(i/9 - 1), s1 = (float)((i/3)%3 - 1), s2 = (float)(i%3 - 1);
        sv[i*3+0] = s0*L.lx + s1*L.xy + s2*L.xz;
        sv[i*3+1] = s1*L.ly + s2*L.yz;
        sv[i*3+2] = s2*L.lz;
    }
}

// Per-atom top-24 + fused RBF. One 64-lane wave per atom (min-image fast path).
__global__ __launch_bounds__(64) void knn_kernel(
        const float* __restrict__ cxg, const float* __restrict__ cyg,
        const float* __restrict__ czg, const float* __restrict__ lengths,
        const float* __restrict__ angles, const float* __restrict__ sv,
        int* __restrict__ dstl, ushort* __restrict__ rbf16) {
    __shared__ float sd2L[16][64];
    __shared__ int   sfL[16][64];
    const int lane = threadIdx.x;
    const int i = blockIdx.x;
    Lat L = make_lattice(lengths, angles);
    const float deg = 0.017453292519943295f;
    const bool ortho = fabsf(cosf(angles[0]*deg)) < 1e-6f &&
                       fabsf(cosf(angles[1]*deg)) < 1e-6f &&
                       fabsf(cosf(angles[2]*deg)) < 1e-6f;
    const float cx = cxg[i], cy = cyg[i], cz = czg[i];
    const float invlx = 1.0f/L.lx, invly = 1.0f/L.ly, invlz = 1.0f/L.lz;
    float R = 2.8f;
    int mycnt = 0, cnt = 0;
    bool flatm = false;
    for (int attempt = 0; attempt < 8; ++attempt) {
        const float R2 = R*R;
        mycnt = 0;
        flatm = !ortho || (attempt == 7);
        if (!flatm) {
#pragma unroll 2
            for (int j0 = 0; j0 < NA; j0 += 64) {
                const int j = j0 + lane;
                const float dx = cxg[j] - cx, dy = cyg[j] - cy, dz = czg[j] - cz;
                const float kx = rintf(dx*invlx), ky = rintf(dy*invly), kz = rintf(dz*invlz);
                const float ex = dx - (kx*L.lx + ky*L.xy + kz*L.xz);
                const float ey = dy - (ky*L.ly + kz*L.yz);
                const float ez = dz - kz*L.lz;
                const float d2 = fmaf(ex,ex,fmaf(ey,ey,ez*ez));
                if (d2 < R2 && d2 > 1e-4f) {
                    const int s = (1-(int)kx)*9 + (1-(int)ky)*3 + (1-(int)kz);
                    if (mycnt < 16) { sd2L[mycnt][lane] = d2; sfL[mycnt][lane] = (s<<11) + j; }
                    ++mycnt;
                }
            }
            if (__ballot(mycnt > 16)) {
                flatm = true;
            } else {
                int tot = mycnt;
                for (int off = 32; off > 0; off >>= 1) tot += __shfl_xor(tot, off, 64);
                cnt = tot;
            }
        }
        if (flatm) {
            cnt = 0;
            for (int s = 0; s < 27; ++s) {
                const float svx = sv[s*3], svy = sv[s*3+1], svz = sv[s*3+2];
                for (int j0 = 0; j0 < NA; j0 += 64) {
                    const int j = j0 + lane;
                    const float ex = cxg[j] + svx - cx;
                    const float ey = cyg[j] + svy - cy;
                    const float ez = czg[j] + svz - cz;
                    const float d2 = fmaf(ex,ex,fmaf(ey,ey,ez*ez));
                    const bool hit = (d2 < R2) && (d2 > 1e-4f);
                    const unsigned long long m = __ballot(hit);
                    const int rank = __popcll(m & ((1ull<<lane)-1ull));
                    const int slot = cnt + rank;
                    if (hit && slot < 1024) { sd2L[slot>>6][slot&63] = d2; sfL[slot>>6][slot&63] = (s<<11)+j; }
                    cnt += __popcll(m);
                }
            }
            cnt = min(cnt, 1024);
        }
        if (cnt >= KN) break;
        R = fminf(R*1.6f, flatm ? 8.0f : 5.9f);
    }
    int vq;
    if (flatm) vq = (lane < cnt) ? min(16, ((cnt - 1 - lane) >> 6) + 1) : 0;
    else       vq = mycnt;
    unsigned long long key[16];
#pragma unroll
    for (int q = 0; q < 16; ++q) {
        const float d2v = sd2L[q][lane];
        const int fl = sfL[q][lane];
        const unsigned long long kk = ((unsigned long long)__float_as_uint(d2v) << 20)
                                    | ((unsigned long long)(unsigned)fl << 4) | (unsigned)q;
        key[q] = (q < vq) ? kk : ~0ull;
    }
    float der[KN];
    for (int k = 0; k < KN; ++k) {
        unsigned long long lm = key[0];
#pragma unroll
        for (int q = 1; q < 16; ++q) lm = key[q] < lm ? key[q] : lm;
        for (int off = 32; off > 0; off >>= 1) {
            unsigned long long o = __shfl_xor(lm, off, 64);
            lm = o < lm ? o : lm;
        }
        der[k] = sqrtf(__uint_as_float((unsigned)(lm >> 20)));
        if (lane == 0) dstl[i*KN + k] = (int)((lm >> 4) & 2047u);
#pragma unroll
        for (int q = 0; q < 16; ++q) if (key[q] == lm) key[q] = ~0ull;
    }
    const float center = (8.0f/63.0f) * (float)lane;
    for (int k = 0; k < KN; ++k) {
        const float d = der[k];
        const float diff = d - center;
        const float g = expf(diff*diff * -32.0f);
        const float cv = 0.5f * (cosf(d * (float)(M_PI/8.0)) + 1.0f);
        rbf16[(size_t)(i*KN + k)*EDIM + lane] = f2b(g * cv);
    }
}

__global__ void scatter_kernel(const int* __restrict__ dstl, int* __restrict__ ccnt,
                               int* __restrict__ cedg) {
    int e = blockIdx.x*256 + threadIdx.x;
    if (e >= NE) return;
    int j = dstl[e];
    int slot = atomicAdd(&ccnt[j], 1);
    if (slot < MAXDEG) cedg[(size_t)j*MAXDEG + slot] = e;
}

__global__ void csort_kernel(const int* __restrict__ ccnt, int* __restrict__ cedg) {
    const int j = blockIdx.x*4 + (threadIdx.x >> 6);
    const int lane = threadIdx.x & 63;
    const int cnt = min(ccnt[j], MAXDEG);
    if (cnt <= 64) {
        int v = (lane < cnt) ? cedg[(size_t)j*MAXDEG + lane] : 0x7FFFFFFF;
#pragma unroll
        for (int k = 2; k <= 64; k <<= 1) {
#pragma unroll
            for (int s = k >> 1; s > 0; s >>= 1) {
                int o = __shfl_xor(v, s, 64);
                const bool up = ((lane & k) == 0);
                const bool lowhalf = ((lane & s) == 0);
                v = ((lowhalf == up) ? min(v, o) : max(v, o));
            }
        }
        if (lane < cnt) cedg[(size_t)j*MAXDEG + lane] = v;
    } else if (lane == 0) {
        int* L = cedg + (size_t)j*MAXDEG;
        for (int a = 1; a < cnt; ++a) {
            int v = L[a]; int b = a - 1;
            while (b >= 0 && L[b] > v) { L[b+1] = L[b]; --b; }
            L[b+1] = v;
        }
    }
}

__global__ void nf_init_kernel(const int* __restrict__ atom_types, const float* __restrict__ ts,
                               const float* __restrict__ emb, const float* __restrict__ tW,
                               const float* __restrict__ tb, float* __restrict__ nf,
                               ushort* __restrict__ nf16) {
    int i = blockIdx.x, c = threadIdx.x;  // 128 threads
    float acc = emb[atom_types[i]*NDIM + c] + tb[c];
    for (int kk = 0; kk < 128; ++kk) acc += ts[i*128 + kk] * tW[kk*NDIM + c];
    nf[i*NDIM + c] = acc;
    nf16[i*NDIM + c] = f2b(acc);
}

// LDS-tiled transpose+convert to Bt layouts. eW1 split:
//   rows 0..127 -> eW1abt rows 0..255 (src part, Kd=128), rows 128..255 -> eW1abt rows 256..511,
//   rows 256..319 -> eW1ct [256][64].
__global__ void wprep_all(const float* __restrict__ eW1, const float* __restrict__ eW2,
                          const float* __restrict__ cW1, const float* __restrict__ nW1,
                          const float* __restrict__ nW2,
                          ushort* __restrict__ eW1abt, ushort* __restrict__ eW1ct,
                          ushort* __restrict__ eW2t, ushort* __restrict__ cW1t,
                          ushort* __restrict__ nW1t, ushort* __restrict__ nW2t) {
    __shared__ float tile[64][65];
    const int b = blockIdx.x;
    int l, kt, nt, Kk, Nn, Kd, n0d, k0d;
    const float* Wl; ushort* Wd;
    if (b < 80) {
        int rel = b; l = rel/20; int r = rel%20; kt = r/4; nt = r%4;
        Kk = 320; Nn = 256; Wl = eW1 + (size_t)l*Kk*Nn;
        if (kt < 2)      { Wd = eW1abt + (size_t)l*512*128; Kd = 128; n0d = nt*64;       k0d = kt*64; }
        else if (kt < 4) { Wd = eW1abt + (size_t)l*512*128; Kd = 128; n0d = nt*64 + 256; k0d = (kt-2)*64; }
        else             { Wd = eW1ct  + (size_t)l*256*64;  Kd = 64;  n0d = nt*64;       k0d = 0; }
    } else if (b < 144) {
        int rel = b-80; l = rel/16; int r = rel%16; kt = r/4; nt = r%4;
        Kk = 256; Nn = 256; Wl = eW2 + (size_t)l*Kk*Nn; Wd = eW2t + (size_t)l*Kk*Nn;
        Kd = 256; n0d = nt*64; k0d = kt*64;
    } else if (b < 176) {
        int rel = b-144; l = rel/8; int r = rel%8; kt = r/2; nt = r%2;
        Kk = 256; Nn = 128; Wl = cW1 + (size_t)l*Kk*Nn; Wd = cW1t + (size_t)l*Kk*Nn;
        Kd = 256; n0d = nt*64; k0d = kt*64;
    } else if (b < 272) {
        int rel = b-176; l = rel/24; int r = rel%24; kt = r/4; nt = r%4;
        Kk = 384; Nn = 256; Wl = nW1 + (size_t)l*Kk*Nn; Wd = nW1t + (size_t)l*Kk*Nn;
        Kd = 384; n0d = nt*64; k0d = kt*64;
    } else {
        int rel = b-272; l = rel/8; int r = rel%8; kt = r/2; nt = r%2;
        Kk = 256; Nn = 128; Wl = nW2 + (size_t)l*Kk*Nn; Wd = nW2t + (size_t)l*Kk*Nn;
        Kd = 256; n0d = nt*64; k0d = kt*64;
    }
    const int k0 = kt*64, n0 = nt*64;
    const int tr = threadIdx.x >> 6, tc = threadIdx.x & 63;
#pragma unroll
    for (int q = 0; q < 16; ++q) {
        const int k = q*4 + tr;
        tile[k][tc] = Wl[(size_t)(k0 + k)*Nn + n0 + tc];
    }
    __syncthreads();
#pragma unroll
    for (int q = 0; q < 16; ++q) {
        const int n = q*4 + tr;
        Wd[(size_t)(n0d + n)*Kd + k0d + tc] = f2b(tile[tc][n]);
    }
}

// bf16 MFMA GEMM, 128x128 tile, BK=32, counted-vmcnt double buffer (R6-proven structure).
// AMODE: 0 dense A | 2 ncat [nf16|aggr16]
// EPI: 0 bias+silu -> bf16 | 1 raw -> bf16 | 2 bias+res -> fp32 Cf AND bf16 C16
//      3 fused wdot: wv[row] = sum_col silu(acc+bias)*cW2[col] + cb2
//      4 h1: silu(acc + bias + P16[src*512+cc] + P16[dst*512+256+cc]) -> bf16
template<int AMODE, int EPI>
__global__ __launch_bounds__(256) void bgemm_kernel(
        const ushort* __restrict__ A, const ushort* __restrict__ nf16,
        const ushort* __restrict__ aggr16, const int* __restrict__ dstl,
        const ushort* __restrict__ P16, const ushort* __restrict__ Bt,
        const float* __restrict__ bias, const float* __restrict__ res,
        const float* __restrict__ cW2v, const float* __restrict__ cb2v,
        float* __restrict__ wvout,
        float* __restrict__ Cf, ushort* __restrict__ C16, int M, int Nn, int Kk) {
    __shared__ alignas(16) ushort As[2][128*32];
    __shared__ alignas(16) ushort Bs[2][128*32];
    __shared__ int sdst[128];
    const int t = threadIdx.x;
    const int wave = t >> 6, lane = t & 63;
    const int row0 = blockIdx.x*128, col0 = blockIdx.y*128;
    if (EPI == 4) {
        if (t < 128) sdst[t] = dstl[row0 + t];
        __syncthreads();
    }
    const int wr = (wave >> 1)*64, wc = (wave & 1)*64;
    const int lr = lane & 15, g0 = lane >> 4;

    auto STAGE = [&](int buf, int k0) {
#pragma unroll
        for (int q = 0; q < 4; ++q) {
            const int rbase = (q & 1)*64 + wave*16;
            const int r = rbase + (lane >> 2);
            const int g = (lane & 3) ^ ((r >> 1) & 3);
            const int kg = k0 + g*8;
            const int ldsbase = rbase * 32;
            if (q < 2) {
                const ushort* gp;
                if (AMODE == 0) {
                    gp = A + (size_t)(row0 + r)*Kk + kg;
                } else {
                    const int e = row0 + r;
                    if (kg < NDIM) gp = nf16 + (size_t)e*NDIM + kg;
                    else           gp = aggr16 + (size_t)e*HDIM + (kg - NDIM);
                }
                gl_lds(gp, &As[buf][ldsbase]);
            } else {
                gl_lds(Bt + (size_t)(col0 + r)*Kk + kg, &Bs[buf][ldsbase]);
            }
        }
    };

    f32x4 acc[4][4] = {};
    const int nk = Kk >> 5;
    STAGE(0, 0);
    int cur = 0;
    for (int it = 0; it < nk; ++it) {
        if (it + 1 < nk) {
            STAGE(cur ^ 1, (it + 1) << 5);
            asm volatile("s_waitcnt vmcnt(4)" ::: "memory");
        } else {
            asm volatile("s_waitcnt vmcnt(0)" ::: "memory");
        }
        __builtin_amdgcn_sched_barrier(0);
        __builtin_amdgcn_s_barrier();
        __builtin_amdgcn_sched_barrier(0);
        bf16x8 af[4], bfr[4];
#pragma unroll
        for (int m = 0; m < 4; ++m) {
            const int rA = wr + m*16 + lr;
            af[m] = *reinterpret_cast<const bf16x8*>(&As[cur][rA*32 + (g0 ^ ((rA>>1)&3))*8]);
        }
#pragma unroll
        for (int n = 0; n < 4; ++n) {
            const int rB = wc + n*16 + lr;
            bfr[n] = *reinterpret_cast<const bf16x8*>(&Bs[cur][rB*32 + (g0 ^ ((rB>>1)&3))*8]);
        }
#pragma unroll
        for (int m = 0; m < 4; ++m)
#pragma unroll
            for (int n = 0; n < 4; ++n)
                acc[m][n] = __builtin_amdgcn_mfma_f32_16x16x32_bf16(af[m], bfr[n], acc[m][n], 0, 0, 0);
        asm volatile("s_waitcnt lgkmcnt(0)" ::: "memory");
        __builtin_amdgcn_sched_barrier(0);
        __builtin_amdgcn_s_barrier();
        __builtin_amdgcn_sched_barrier(0);
        cur ^= 1;
    }

    if constexpr (EPI == 3) {
        __shared__ float wred[2][128];
        float part[4][4];
#pragma unroll
        for (int m = 0; m < 4; ++m)
#pragma unroll
            for (int j = 0; j < 4; ++j) part[m][j] = 0.0f;
#pragma unroll
        for (int n = 0; n < 4; ++n) {
            const int cc = wc + n*16 + lr;       // col0 == 0 (Nn=128)
            const float bb = bias[cc];
            const float cw = cW2v[cc];
#pragma unroll
            for (int m = 0; m < 4; ++m)
#pragma unroll
                for (int j = 0; j < 4; ++j)
                    part[m][j] += siluf(acc[m][n][j] + bb) * cw;
        }
#pragma unroll
        for (int off = 1; off < 16; off <<= 1)
#pragma unroll
            for (int m = 0; m < 4; ++m)
#pragma unroll
                for (int j = 0; j < 4; ++j)
                    part[m][j] += __shfl_xor(part[m][j], off, 64);
        if (lr == 0) {
#pragma unroll
            for (int m = 0; m < 4; ++m)
#pragma unroll
                for (int j = 0; j < 4; ++j)
                    wred[wave & 1][wr + m*16 + g0*4 + j] = part[m][j];
        }
        __syncthreads();
        if (t < 128) wvout[row0 + t] = wred[0][t] + wred[1][t] + cb2v[0];
        return;
    }

    // C/D layout: col = lane&15, row = (lane>>4)*4 + j
#pragma unroll
    for (int n = 0; n < 4; ++n) {
        const int cc = col0 + wc + n*16 + lr;
        const float bb = (EPI == 1) ? 0.0f : bias[cc];
#pragma unroll
        for (int m = 0; m < 4; ++m) {
#pragma unroll
            for (int j = 0; j < 4; ++j) {
                const int rr = row0 + wr + m*16 + (lane >> 4)*4 + j;
                float x = acc[m][n][j] + bb;
                if constexpr (EPI == 0) {
                    C16[(size_t)rr*Nn + cc] = f2b(siluf(x));
                } else if constexpr (EPI == 1) {
                    C16[(size_t)rr*Nn + cc] = f2b(x);
                } else if constexpr (EPI == 2) {
                    x += res[(size_t)rr*Nn + cc];
                    Cf[(size_t)rr*Nn + cc] = x;
                    C16[(size_t)rr*Nn + cc] = f2b(x);
                } else {  // EPI == 4: h1 = silu(acc + eb1 + Psrc + Pdst)
                    const int srci = rr / KN;
                    const int dstj = sdst[rr - row0];
                    x += b2f(P16[(size_t)srci*512 + cc]);
                    x += b2f(P16[(size_t)dstj*512 + 256 + cc]);
                    C16[(size_t)rr*Nn + cc] = f2b(siluf(x));
                }
            }
        }
    }
}

// aggr16[j,:] = bf16( sum over incoming edges of msg[e,:] ), one wave per node
__global__ void aggr_kernel(const ushort* __restrict__ msg16, const int* __restrict__ ccnt,
                            const int* __restrict__ cedg, ushort* __restrict__ aggr16) {
    __shared__ int se[4][64];
    const int w = threadIdx.x >> 6, lane = threadIdx.x & 63;
    const int j = blockIdx.x*4 + w;
    const int cnt = min(ccnt[j], MAXDEG);
    se[w][lane] = (lane < cnt) ? cedg[(size_t)j*MAXDEG + lane] : 0;
    __syncthreads();
    const int c4 = lane*4;
    float s0 = 0, s1 = 0, s2 = 0, s3 = 0;
    const int lim = min(cnt, 64);
    for (int q = 0; q < lim; ++q) {
        const int e = se[w][q];
        ushort4 v = *reinterpret_cast<const ushort4*>(&msg16[(size_t)e*HDIM + c4]);
        s0 += b2f(v.x); s1 += b2f(v.y); s2 += b2f(v.z); s3 += b2f(v.w);
    }
    for (int q = 64; q < cnt; ++q) {
        const int e = cedg[(size_t)j*MAXDEG + q];
        ushort4 v = *reinterpret_cast<const ushort4*>(&msg16[(size_t)e*HDIM + c4]);
        s0 += b2f(v.x); s1 += b2f(v.y); s2 += b2f(v.z); s3 += b2f(v.w);
    }
    ushort4 o; o.x = f2b(s0); o.y = f2b(s1); o.z = f2b(s2); o.w = f2b(s3);
    *reinterpret_cast<ushort4*>(&aggr16[(size_t)j*HDIM + c4]) = o;
}

// coords update: one wave per node, lanes parallel over edges
__global__ void coords_kernel(const float* __restrict__ cold, const float* __restrict__ wv,
                              const int* __restrict__ ccnt, const int* __restrict__ cedg,
                              float* __restrict__ cnew) {
    const int w = threadIdx.x >> 6, lane = threadIdx.x & 63;
    const int j = blockIdx.x*4 + w;
    const int cnt = min(ccnt[j], MAXDEG);
    const float jx = cold[j*3], jy = cold[j*3+1], jz = cold[j*3+2];
    float dx = 0, dy = 0, dz = 0;
    for (int q = lane; q < cnt; q += 64) {
        const int e = cedg[(size_t)j*MAXDEG + q];
        const int si = e / KN;
        const float ax = cold[si*3]   - jx;
        const float ay = cold[si*3+1] - jy;
        const float az = cold[si*3+2] - jz;
        const float inv = wv[e] / (sqrtf(ax*ax + ay*ay + az*az) + 1e-8f);
        dx += inv*ax; dy += inv*ay; dz += inv*az;
    }
    for (int off = 32; off > 0; off >>= 1) {
        dx += __shfl_xor(dx, off, 64);
        dy += __shfl_xor(dy, off, 64);
        dz += __shfl_xor(dz, off, 64);
    }
    if (lane == 0) {
        cnew[j*3]   = jx + dx;
        cnew[j*3+1] = jy + dy;
        cnew[j*3+2] = jz + dz;
    }
}

__global__ void copyout_kernel(const float* __restrict__ nf, const float* __restrict__ coords,
                               float* __restrict__ out) {
    int idx = blockIdx.x*256 + threadIdx.x;
    if (idx < NA*NDIM) out[idx] = nf[idx];
    else if (idx < NA*NDIM + NA*3) out[idx] = coords[idx - NA*NDIM];
}

extern "C" void kernel_launch(void* const* d_in, const int* in_sizes, int n_in,
                              void* d_out, int out_size, void* d_ws, size_t ws_size,
                              hipStream_t stream) {
    const int*   atom_types = (const int*)  d_in[0];
    const float* frac       = (const float*)d_in[1];
    const float* lengths    = (const float*)d_in[2];
    const float* angles     = (const float*)d_in[3];
    const float* timesteps  = (const float*)d_in[4];
    const float* emb        = (const float*)d_in[5];
    const float* tW         = (const float*)d_in[6];
    const float* tb         = (const float*)d_in[7];
    const float* eW1        = (const float*)d_in[8];
    const float* eb1        = (const float*)d_in[9];
    const float* eW2        = (const float*)d_in[10];
    const float* eb2        = (const float*)d_in[11];
    const float* nW1        = (const float*)d_in[12];
    const float* nb1        = (const float*)d_in[13];
    const float* nW2        = (const float*)d_in[14];
    const float* nb2        = (const float*)d_in[15];
    const float* cW1        = (const float*)d_in[16];
    const float* cb1        = (const float*)d_in[17];
    const float* cW2        = (const float*)d_in[18];
    const float* cb2        = (const float*)d_in[19];

    char* p = (char*)d_ws;
    auto alloc = [&](size_t bytes) { char* q = p; p += (bytes + 255) & ~(size_t)255; return q; };
    float*  sv    = (float*) alloc(81*4);
    float*  c0    = (float*) alloc((size_t)NA*3*4);
    float*  c1    = (float*) alloc((size_t)NA*3*4);
    float*  cxg   = (float*) alloc((size_t)NA*4);
    float*  cyg   = (float*) alloc((size_t)NA*4);
    float*  czg   = (float*) alloc((size_t)NA*4);
    float*  nf    = (float*) alloc((size_t)NA*NDIM*4);
    int*    dstl  = (int*)   alloc((size_t)NE*4);
    ushort* rbf16 = (ushort*)alloc((size_t)NE*EDIM*2);
    int*    ccnt  = (int*)   alloc((size_t)NA*4);
    int*    cedg  = (int*)   alloc((size_t)NA*MAXDEG*4);
    ushort* aggr16= (ushort*)alloc((size_t)NA*HDIM*2);
    ushort* t116  = (ushort*)alloc((size_t)NA*HDIM*2);
    float*  wv    = (float*) alloc((size_t)NE*4);
    ushort* nf16  = (ushort*)alloc((size_t)NA*NDIM*2);
    ushort* P16   = (ushort*)alloc((size_t)NA*512*2);
    ushort* h116  = (ushort*)alloc((size_t)NE*HDIM*2);
    ushort* msg16 = (ushort*)alloc((size_t)NE*HDIM*2);
    ushort* eW1abt= (ushort*)alloc((size_t)NLAYER*512*128*2);
    ushort* eW1ct = (ushort*)alloc((size_t)NLAYER*256*64*2);
    ushort* eW2t  = (ushort*)alloc((size_t)NLAYER*HDIM*HDIM*2);
    ushort* cW1t  = (ushort*)alloc((size_t)NLAYER*(HDIM/2)*HDIM*2);
    ushort* nW1t  = (ushort*)alloc((size_t)NLAYER*(NDIM+HDIM)*HDIM*2);
    ushort* nW2t  = (ushort*)alloc((size_t)NLAYER*HDIM*NDIM*2);

    setup_kernel<<<8, 256, 0, stream>>>(frac, lengths, angles, c0, cxg, cyg, czg, sv);
    knn_kernel<<<NA, 64, 0, stream>>>(cxg, cyg, czg, lengths, angles, sv, dstl, rbf16);
    hipMemsetAsync(ccnt, 0, (size_t)NA*4, stream);
    scatter_kernel<<<NE/256, 256, 0, stream>>>(dstl, ccnt, cedg);
    csort_kernel<<<NA/4, 256, 0, stream>>>(ccnt, cedg);
    nf_init_kernel<<<NA, 128, 0, stream>>>(atom_types, timesteps, emb, tW, tb, nf, nf16);
    wprep_all<<<304, 256, 0, stream>>>(eW1, eW2, cW1, nW1, nW2,
                                       eW1abt, eW1ct, eW2t, cW1t, nW1t, nW2t);

    float* cin = c0; float* cout = c1;
    for (int l = 0; l < NLAYER; ++l) {
        const float* eb1l = eb1 + (size_t)l*HDIM;
        const float* eb2l = eb2 + (size_t)l*HDIM;
        const float* nb1l = nb1 + (size_t)l*HDIM;
        const float* nb2l = nb2 + (size_t)l*NDIM;
        const float* cb1l = cb1 + (size_t)l*(HDIM/2);
        const float* cW2l = cW2 + (size_t)l*(HDIM/2);
        const float* cb2l = cb2 + (size_t)l;

        // P = nf16 @ [W1a|W1b]   (2048x512, K=128, raw)
        bgemm_kernel<0,1><<<dim3(NA/128, 4), 256, 0, stream>>>(
            nf16, nullptr, nullptr, nullptr, nullptr, eW1abt + (size_t)l*512*128,
            nullptr, nullptr, nullptr, nullptr, nullptr, nullptr, P16, NA, 512, 128);
        // h1 = silu(rbf @ W1c + P[src] + P[dst,+256] + eb1)   (K=64)
        bgemm_kernel<0,4><<<dim3(NE/128, HDIM/128), 256, 0, stream>>>(
            rbf16, nullptr, nullptr, dstl, P16, eW1ct + (size_t)l*256*64,
            eb1l, nullptr, nullptr, nullptr, nullptr, nullptr, h116, NE, HDIM, EDIM);
        // msg = silu(h1 @ eW2 + eb2)
        bgemm_kernel<0,0><<<dim3(NE/128, HDIM/128), 256, 0, stream>>>(
            h116, nullptr, nullptr, nullptr, nullptr, eW2t + (size_t)l*HDIM*HDIM,
            eb2l, nullptr, nullptr, nullptr, nullptr, nullptr, msg16, NE, HDIM, HDIM);
        // aggr = segment_sum(msg, dst)
        aggr_kernel<<<NA/4, 256, 0, stream>>>(msg16, ccnt, cedg, aggr16);
        // t1 = silu([nf|aggr] @ nW1 + nb1)
        bgemm_kernel<2,0><<<dim3(NA/128, HDIM/128), 256, 0, stream>>>(
            nullptr, nf16, aggr16, nullptr, nullptr, nW1t + (size_t)l*(NDIM+HDIM)*HDIM,
            nb1l, nullptr, nullptr, nullptr, nullptr, nullptr, t116, NA, HDIM, NDIM+HDIM);
        // nf = nf + t1 @ nW2 + nb2
        bgemm_kernel<0,2><<<dim3(NA/128, NDIM/128), 256, 0, stream>>>(
            t116, nullptr, nullptr, nullptr, nullptr, nW2t + (size_t)l*HDIM*NDIM,
            nb2l, nf, nullptr, nullptr, nullptr, nf, nf16, NA, NDIM, HDIM);
        // wv = silu(msg @ cW1 + cb1) @ cW2 + cb2
        bgemm_kernel<0,3><<<dim3(NE/128, 1), 256, 0, stream>>>(
            msg16, nullptr, nullptr, nullptr, nullptr, cW1t + (size_t)l*(HDIM/2)*HDIM,
            cb1l, nullptr, cW2l, cb2l, wv, nullptr, nullptr, NE, HDIM/2, HDIM);
        // coords update
        coords_kernel<<<NA/4, 256, 0, stream>>>(cin, wv, ccnt, cedg, cout);
        float* tmp = cin; cin = cout; cout = tmp;
    }
    copyout_kernel<<<(NA*NDIM + NA*3)/256, 256, 0, stream>>>(nf, cin, (float*)d_out);
}

// Round 9
// 418.115 us; speedup vs baseline: 1.2928x; 1.0898x over previous
//
#include <hip/hip_runtime.h>
#include <math.h>

#define NA 2048          // atoms
#define KN 24            // neighbors per atom
#define NE (NA*KN)       // edges = 49152
#define NDIM 128         // node dim
#define EDIM 64          // rbf dim
#define HDIM 256         // hidden dim
#define NLAYER 4
#define MAXDEG 256       // cap on in-degree for CSR

typedef __attribute__((ext_vector_type(8))) short bf16x8;
typedef __attribute__((ext_vector_type(4))) float f32x4;

__device__ __forceinline__ float siluf(float x) { return x / (1.0f + expf(-x)); }
__device__ __forceinline__ ushort f2b(float x) {  // RNE float->bf16
    unsigned u = __float_as_uint(x);
    return (ushort)((u + 0x7fffu + ((u >> 16) & 1u)) >> 16);
}
__device__ __forceinline__ float b2f(ushort h) { return __uint_as_float(((unsigned)h) << 16); }

// async global->LDS, 16B per lane. LDS dest = wave-uniform base + lane*16 (linear).
__device__ __forceinline__ void gl_lds(const void* g, void* lds) {
    __builtin_amdgcn_global_load_lds(
        (const __attribute__((address_space(1))) unsigned int*)g,
        (__attribute__((address_space(3))) unsigned int*)lds, 16, 0, 0);
}

struct Lat { float lx, xy, xz, ly, yz, lz; };

__device__ __forceinline__ Lat make_lattice(const float* lengths, const float* angles) {
    const float deg = 0.017453292519943295f;
    float a = lengths[0], b = lengths[1], c = lengths[2];
    float al = angles[0]*deg, be = angles[1]*deg, ga = angles[2]*deg;
    Lat L;
    L.lx = a;
    L.xy = b * cosf(ga);
    L.xz = c * cosf(be);
    L.ly = b * sinf(ga);
    L.yz = (b*c*cosf(al) - L.xy*L.xz) / L.ly;
    L.lz = sqrtf(c*c - L.xz*L.xz - L.yz*L.yz);
    return L;
}

// writes AoS cart + SoA cx/cy/cz; also zeroes ccnt (used by knn's fused scatter)
__global__ void setup_kernel(const float* __restrict__ frac, const float* __restrict__ lengths,
                             const float* __restrict__ angles, float* __restrict__ cart,
                             float* __restrict__ cxg, float* __restrict__ cyg,
                             float* __restrict__ czg, float* __restrict__ sv,
                             int* __restrict__ ccnt) {
    int i = blockIdx.x*blockDim.x + threadIdx.x;
    Lat L = make_lattice(lengths, angles);
    if (i < NA) {
        float f0 = frac[i*3], f1 = frac[i*3+1], f2 = frac[i*3+2];
        float x = f0*L.lx + f1*L.xy + f2*L.xz;
        float y = f1*L.ly + f2*L.yz;
        float z = f2*L.lz;
        cart[i*3+0] = x; cart[i*3+1] = y; cart[i*3+2] = z;
        cxg[i] = x; cyg[i] = y; czg[i] = z;
        ccnt[i] = 0;
    }
    if (i < 27) {
        float s0 = (float)(i/9 - 1), s1 = (float)((i/3)%3 - 1), s2 = (float)(i%3 - 1);
        sv[i*3+0] = s0*L.lx + s1*L.xy + s2*L.xz;
        sv[i*3+1] = s1*L.ly + s2*L.yz;
        sv[i*3+2] = s2*L.lz;
    }
}

// Per-atom top-24 + fused RBF + fused CSR scatter. One 64-lane wave per atom.
__global__ __launch_bounds__(64) void knn_kernel(
        const float* __restrict__ cxg, const float* __restrict__ cyg,
        const float* __restrict__ czg, const float* __restrict__ lengths,
        const float* __restrict__ angles, const float* __restrict__ sv,
        int* __restrict__ dstl, ushort* __restrict__ rbf16,
        int* __restrict__ ccnt, int* __restrict__ cedg) {
    __shared__ float sd2L[16][64];
    __shared__ int   sfL[16][64];
    const int lane = threadIdx.x;
    const int i = blockIdx.x;
    Lat L = make_lattice(lengths, angles);
    const float deg = 0.017453292519943295f;
    const bool ortho = fabsf(cosf(angles[0]*deg)) < 1e-6f &&
                       fabsf(cosf(angles[1]*deg)) < 1e-6f &&
                       fabsf(cosf(angles[2]*deg)) < 1e-6f;
    const float cx = cxg[i], cy = cyg[i], cz = czg[i];
    const float invlx = 1.0f/L.lx, invly = 1.0f/L.ly, invlz = 1.0f/L.lz;
    float R = 2.8f;
    int mycnt = 0, cnt = 0;
    bool flatm = false;
    for (int attempt = 0; attempt < 8; ++attempt) {
        const float R2 = R*R;
        mycnt = 0;
        flatm = !ortho || (attempt == 7);
        if (!flatm) {
#pragma unroll 2
            for (int j0 = 0; j0 < NA; j0 += 64) {
                const int j = j0 + lane;
                const float dx = cxg[j] - cx, dy = cyg[j] - cy, dz = czg[j] - cz;
                const float kx = rintf(dx*invlx), ky = rintf(dy*invly), kz = rintf(dz*invlz);
                const float ex = dx - (kx*L.lx + ky*L.xy + kz*L.xz);
                const float ey = dy - (ky*L.ly + kz*L.yz);
                const float ez = dz - kz*L.lz;
                const float d2 = fmaf(ex,ex,fmaf(ey,ey,ez*ez));
                if (d2 < R2 && d2 > 1e-4f) {
                    const int s = (1-(int)kx)*9 + (1-(int)ky)*3 + (1-(int)kz);
                    if (mycnt < 16) { sd2L[mycnt][lane] = d2; sfL[mycnt][lane] = (s<<11) + j; }
                    ++mycnt;
                }
            }
            if (__ballot(mycnt > 16)) {
                flatm = true;
            } else {
                int tot = mycnt;
                for (int off = 32; off > 0; off >>= 1) tot += __shfl_xor(tot, off, 64);
                cnt = tot;
            }
        }
        if (flatm) {
            cnt = 0;
            for (int s = 0; s < 27; ++s) {
                const float svx = sv[s*3], svy = sv[s*3+1], svz = sv[s*3+2];
                for (int j0 = 0; j0 < NA; j0 += 64) {
                    const int j = j0 + lane;
                    const float ex = cxg[j] + svx - cx;
                    const float ey = cyg[j] + svy - cy;
                    const float ez = czg[j] + svz - cz;
                    const float d2 = fmaf(ex,ex,fmaf(ey,ey,ez*ez));
                    const bool hit = (d2 < R2) && (d2 > 1e-4f);
                    const unsigned long long m = __ballot(hit);
                    const int rank = __popcll(m & ((1ull<<lane)-1ull));
                    const int slot = cnt + rank;
                    if (hit && slot < 1024) { sd2L[slot>>6][slot&63] = d2; sfL[slot>>6][slot&63] = (s<<11)+j; }
                    cnt += __popcll(m);
                }
            }
            cnt = min(cnt, 1024);
        }
        if (cnt >= KN) break;
        R = fminf(R*1.6f, flatm ? 8.0f : 5.9f);
    }
    int vq;
    if (flatm) vq = (lane < cnt) ? min(16, ((cnt - 1 - lane) >> 6) + 1) : 0;
    else       vq = mycnt;
    unsigned long long key[16];
#pragma unroll
    for (int q = 0; q < 16; ++q) {
        const float d2v = sd2L[q][lane];
        const int fl = sfL[q][lane];
        const unsigned long long kk = ((unsigned long long)__float_as_uint(d2v) << 20)
                                    | ((unsigned long long)(unsigned)fl << 4) | (unsigned)q;
        key[q] = (q < vq) ? kk : ~0ull;
    }
    float der[KN];
    for (int k = 0; k < KN; ++k) {
        unsigned long long lm = key[0];
#pragma unroll
        for (int q = 1; q < 16; ++q) lm = key[q] < lm ? key[q] : lm;
        for (int off = 32; off > 0; off >>= 1) {
            unsigned long long o = __shfl_xor(lm, off, 64);
            lm = o < lm ? o : lm;
        }
        der[k] = sqrtf(__uint_as_float((unsigned)(lm >> 20)));
        if (lane == 0) {
            const int jn = (int)((lm >> 4) & 2047u);
            dstl[i*KN + k] = jn;
            const int slot = atomicAdd(&ccnt[jn], 1);
            if (slot < MAXDEG) cedg[(size_t)jn*MAXDEG + slot] = i*KN + k;
        }
#pragma unroll
        for (int q = 0; q < 16; ++q) if (key[q] == lm) key[q] = ~0ull;
    }
    const float center = (8.0f/63.0f) * (float)lane;
    for (int k = 0; k < KN; ++k) {
        const float d = der[k];
        const float diff = d - center;
        const float g = expf(diff*diff * -32.0f);
        const float cv = 0.5f * (cosf(d * (float)(M_PI/8.0)) + 1.0f);
        rbf16[(size_t)(i*KN + k)*EDIM + lane] = f2b(g * cv);
    }
}

// one wave per node: 64-lane bitonic sort (ascending), serial fallback for cnt>64
__global__ void csort_kernel(const int* __restrict__ ccnt, int* __restrict__ cedg) {
    const int j = blockIdx.x*4 + (threadIdx.x >> 6);
    const int lane = threadIdx.x & 63;
    const int cnt = min(ccnt[j], MAXDEG);
    if (cnt <= 64) {
        int v = (lane < cnt) ? cedg[(size_t)j*MAXDEG + lane] : 0x7FFFFFFF;
#pragma unroll
        for (int k = 2; k <= 64; k <<= 1) {
#pragma unroll
            for (int s = k >> 1; s > 0; s >>= 1) {
                int o = __shfl_xor(v, s, 64);
                const bool up = ((lane & k) == 0);
                const bool lowhalf = ((lane & s) == 0);
                v = ((lowhalf == up) ? min(v, o) : max(v, o));
            }
        }
        if (lane < cnt) cedg[(size_t)j*MAXDEG + lane] = v;
    } else if (lane == 0) {
        int* L = cedg + (size_t)j*MAXDEG;
        for (int a = 1; a < cnt; ++a) {
            int v = L[a]; int b = a - 1;
            while (b >= 0 && L[b] > v) { L[b+1] = L[b]; --b; }
            L[b+1] = v;
        }
    }
}

__global__ void nf_init_kernel(const int* __restrict__ atom_types, const float* __restrict__ ts,
                               const float* __restrict__ emb, const float* __restrict__ tW,
                               const float* __restrict__ tb, float* __restrict__ nf,
                               ushort* __restrict__ nf16) {
    int i = blockIdx.x, c = threadIdx.x;  // 128 threads
    float acc = emb[atom_types[i]*NDIM + c] + tb[c];
    for (int kk = 0; kk < 128; ++kk) acc += ts[i*128 + kk] * tW[kk*NDIM + c];
    nf[i*NDIM + c] = acc;
    nf16[i*NDIM + c] = f2b(acc);
}

// LDS-tiled transpose+convert: Wt[l][n][k] = bf16(W[l][k][n]). 64x64 tiles. (R6 version)
__global__ void wprep_all(const float* __restrict__ eW1, const float* __restrict__ eW2,
                          const float* __restrict__ cW1, const float* __restrict__ nW1,
                          const float* __restrict__ nW2,
                          ushort* __restrict__ eW1t, ushort* __restrict__ eW2t,
                          ushort* __restrict__ cW1t, ushort* __restrict__ nW1t,
                          ushort* __restrict__ nW2t) {
    __shared__ float tile[64][65];
    const int b = blockIdx.x;
    const float* W; ushort* Wt; int Kk, Nn, rel;
    if (b < 80)       { W = eW1; Wt = eW1t; Kk = 320; Nn = 256; rel = b; }
    else if (b < 144) { W = eW2; Wt = eW2t; Kk = 256; Nn = 256; rel = b - 80; }
    else if (b < 176) { W = cW1; Wt = cW1t; Kk = 256; Nn = 128; rel = b - 144; }
    else if (b < 272) { W = nW1; Wt = nW1t; Kk = 384; Nn = 256; rel = b - 176; }
    else              { W = nW2; Wt = nW2t; Kk = 256; Nn = 128; rel = b - 272; }
    const int kt = Kk >> 6, nt = Nn >> 6, per = kt*nt;
    const int l = rel / per, r2 = rel - l*per;
    const int k0 = (r2 / nt) * 64, n0 = (r2 - (r2/nt)*nt) * 64;
    const float* Wl = W + (size_t)l*Kk*Nn;
    ushort* Wtl = Wt + (size_t)l*Kk*Nn;
    const int tr = threadIdx.x >> 6, tc = threadIdx.x & 63;
#pragma unroll
    for (int q = 0; q < 16; ++q) {
        const int k = q*4 + tr;
        tile[k][tc] = Wl[(size_t)(k0 + k)*Nn + n0 + tc];
    }
    __syncthreads();
#pragma unroll
    for (int q = 0; q < 16; ++q) {
        const int n = q*4 + tr;
        Wtl[(size_t)(n0 + n)*Kk + k0 + tc] = f2b(tile[tc][n]);
    }
}

// Fused edge chain: h1 -> msg -> wv. 64 edges/block, 256 threads (4 waves, 2x2),
// ~74.5KB LDS -> 2 blocks/CU, grid NE/64 = 768.
// Hs (h1/msg tile, 64x256 bf16) swizzle: byte = row*512 + ((col*2) ^ ((row&7)<<4)).
//   - stage B/C A-fragment b128 reads: 2-way bank alias (free)
//   - epilogue scalar writes: <=4-way
__global__ __launch_bounds__(256) void edge_fused(
        const ushort* __restrict__ nf16, const int* __restrict__ dstl,
        const ushort* __restrict__ rbf16,
        const ushort* __restrict__ eW1t,   // [256][320]
        const ushort* __restrict__ eW2t,   // [256][256]
        const ushort* __restrict__ cW1t,   // [128][256]
        const float* __restrict__ eb1, const float* __restrict__ eb2,
        const float* __restrict__ cb1, const float* __restrict__ cW2v,
        const float* __restrict__ cb2v,
        ushort* __restrict__ msg16, float* __restrict__ wvout) {
    __shared__ alignas(16) char R0[40960];   // {As 8K | Bs 32K} -> overlay Hs 32K
    __shared__ alignas(16) char R1[32768];   // {B2 32K} -> overlay {Cs 16K}
    __shared__ int sdst[64];
    __shared__ float wred[2][64];
    ushort* As = (ushort*)R0;                // 2 x [64][32]
    ushort* Bs = (ushort*)(R0 + 8192);       // 2 x [256][32]
    ushort* B2 = (ushort*)R1;                // 2 x [256][32]
    ushort* Cs = (ushort*)R1;                // 2 x [128][32]

    const int t = threadIdx.x, wave = t >> 6, lane = t & 63;
    const int row0 = blockIdx.x*64;
    if (t < 64) sdst[t] = dstl[row0 + t];
    __syncthreads();
    const int wr = (wave >> 1)*32;           // row quarter: 32 rows
    const int wcB = (wave & 1)*128;          // col half for stages A/B (N=256)
    const int lr = lane & 15, g0 = lane >> 4;

    // ---------------- Stage A: h1 = silu(ef @ eW1 + eb1), K=320 ----------------
    auto STAGEA = [&](int buf, int k0) {
        {   // A: 1 issue/wave, rows wave*16..+15
            const int r = wave*16 + (lane >> 2);
            const int g = (lane & 3) ^ ((r >> 1) & 3);
            const int kg = k0 + g*8;
            const int e = row0 + r;
            const ushort* gp;
            if (kg < NDIM)        gp = nf16 + (size_t)(e/KN)*NDIM + kg;
            else if (kg < 2*NDIM) gp = nf16 + (size_t)sdst[r]*NDIM + (kg - NDIM);
            else                  gp = rbf16 + (size_t)e*EDIM + (kg - 2*NDIM);
            gl_lds(gp, As + (size_t)buf*2048 + (wave*16)*32);
        }
#pragma unroll
        for (int q = 0; q < 4; ++q) {        // B: 4 issues/wave, rows wave*64+q*16
            const int rowb = wave*64 + q*16 + (lane >> 2);
            const int g = (lane & 3) ^ ((rowb >> 1) & 3);
            gl_lds(eW1t + (size_t)rowb*320 + k0 + g*8,
                   Bs + (size_t)buf*8192 + (wave*64 + q*16)*32);
        }
    };
    f32x4 acc[2][8];
#pragma unroll
    for (int m = 0; m < 2; ++m)
#pragma unroll
        for (int n = 0; n < 8; ++n) acc[m][n] = (f32x4){0.f,0.f,0.f,0.f};
    STAGEA(0, 0);
    int cur = 0;
    for (int it = 0; it < 10; ++it) {
        if (it + 1 < 10) {
            STAGEA(cur ^ 1, (it + 1)*32);
            asm volatile("s_waitcnt vmcnt(5)" ::: "memory");
        } else {
            asm volatile("s_waitcnt vmcnt(0)" ::: "memory");
        }
        __builtin_amdgcn_sched_barrier(0);
        __builtin_amdgcn_s_barrier();
        __builtin_amdgcn_sched_barrier(0);
        bf16x8 af[2], bfr[8];
#pragma unroll
        for (int m = 0; m < 2; ++m) {
            const int rA = wr + m*16 + lr;
            af[m] = *reinterpret_cast<const bf16x8*>(&As[cur*2048 + rA*32 + ((g0 ^ ((rA>>1)&3)))*8]);
        }
#pragma unroll
        for (int n = 0; n < 8; ++n) {
            const int rB = wcB + n*16 + lr;
            bfr[n] = *reinterpret_cast<const bf16x8*>(&Bs[(size_t)cur*8192 + rB*32 + ((g0 ^ ((rB>>1)&3)))*8]);
        }
#pragma unroll
        for (int m = 0; m < 2; ++m)
#pragma unroll
            for (int n = 0; n < 8; ++n)
                acc[m][n] = __builtin_amdgcn_mfma_f32_16x16x32_bf16(af[m], bfr[n], acc[m][n], 0, 0, 0);
        asm volatile("s_waitcnt lgkmcnt(0)" ::: "memory");
        __builtin_amdgcn_sched_barrier(0);
        __builtin_amdgcn_s_barrier();
        __builtin_amdgcn_sched_barrier(0);
        cur ^= 1;
    }
    // epilogue A: h1 -> Hs (swizzled, overlays As/Bs)
#pragma unroll
    for (int n = 0; n < 8; ++n) {
        const int cc = wcB + n*16 + lr;
        const float b1 = eb1[cc];
#pragma unroll
        for (int m = 0; m < 2; ++m) {
#pragma unroll
            for (int j = 0; j < 4; ++j) {
                const int rr = wr + m*16 + g0*4 + j;
                const float x = siluf(acc[m][n][j] + b1);
                *(ushort*)(R0 + rr*512 + ((cc*2) ^ ((rr&7)<<4))) = f2b(x);
            }
        }
    }
    __syncthreads();

    // ---------------- Stage B: msg = silu(h1 @ eW2 + eb2), K=256 ----------------
#pragma unroll
    for (int m = 0; m < 2; ++m)
#pragma unroll
        for (int n = 0; n < 8; ++n) acc[m][n] = (f32x4){0.f,0.f,0.f,0.f};
    auto STAGEB = [&](int buf, int k0) {
#pragma unroll
        for (int q = 0; q < 4; ++q) {
            const int rowb = wave*64 + q*16 + (lane >> 2);
            const int g = (lane & 3) ^ ((rowb >> 1) & 3);
            gl_lds(eW2t + (size_t)rowb*256 + k0 + g*8,
                   B2 + (size_t)buf*8192 + (wave*64 + q*16)*32);
        }
    };
    STAGEB(0, 0);
    cur = 0;
    for (int it = 0; it < 8; ++it) {
        if (it + 1 < 8) {
            STAGEB(cur ^ 1, (it + 1)*32);
            asm volatile("s_waitcnt vmcnt(4)" ::: "memory");
        } else {
            asm volatile("s_waitcnt vmcnt(0)" ::: "memory");
        }
        __builtin_amdgcn_sched_barrier(0);
        __builtin_amdgcn_s_barrier();
        __builtin_amdgcn_sched_barrier(0);
        bf16x8 af[2], bfr[8];
#pragma unroll
        for (int m = 0; m < 2; ++m) {
            const int rA = wr + m*16 + lr;
            const int kc = it*4 + g0;
            af[m] = *reinterpret_cast<const bf16x8*>(R0 + rA*512 + ((kc*16) ^ ((rA&7)<<4)));
        }
#pragma unroll
        for (int n = 0; n < 8; ++n) {
            const int rB = wcB + n*16 + lr;
            bfr[n] = *reinterpret_cast<const bf16x8*>(&B2[(size_t)cur*8192 + rB*32 + ((g0 ^ ((rB>>1)&3)))*8]);
        }
#pragma unroll
        for (int m = 0; m < 2; ++m)
#pragma unroll
            for (int n = 0; n < 8; ++n)
                acc[m][n] = __builtin_amdgcn_mfma_f32_16x16x32_bf16(af[m], bfr[n], acc[m][n], 0, 0, 0);
        asm volatile("s_waitcnt lgkmcnt(0)" ::: "memory");
        __builtin_amdgcn_sched_barrier(0);
        __builtin_amdgcn_s_barrier();
        __builtin_amdgcn_sched_barrier(0);
        cur ^= 1;
    }
    // epilogue B: msg -> global (for aggr) + Hs in place (for stage C)
#pragma unroll
    for (int n = 0; n < 8; ++n) {
        const int cc = wcB + n*16 + lr;
        const float b2 = eb2[cc];
#pragma unroll
        for (int m = 0; m < 2; ++m) {
#pragma unroll
            for (int j = 0; j < 4; ++j) {
                const int rr = wr + m*16 + g0*4 + j;
                const ushort h = f2b(siluf(acc[m][n][j] + b2));
                msg16[(size_t)(row0 + rr)*256 + cc] = h;
                *(ushort*)(R0 + rr*512 + ((cc*2) ^ ((rr&7)<<4))) = h;
            }
        }
    }
    __syncthreads();

    // ---------------- Stage C: wv = silu(msg @ cW1 + cb1) . cW2 + cb2, K=256 ----------------
    const int wcC = (wave & 1)*64;
    f32x4 acc3[2][4];
#pragma unroll
    for (int m = 0; m < 2; ++m)
#pragma unroll
        for (int n = 0; n < 4; ++n) acc3[m][n] = (f32x4){0.f,0.f,0.f,0.f};
    auto STAGEC = [&](int buf, int k0) {
#pragma unroll
        for (int q = 0; q < 2; ++q) {
            const int rowb = wave*32 + q*16 + (lane >> 2);
            const int g = (lane & 3) ^ ((rowb >> 1) & 3);
            gl_lds(cW1t + (size_t)rowb*256 + k0 + g*8,
                   Cs + (size_t)buf*4096 + (wave*32 + q*16)*32);
        }
    };
    STAGEC(0, 0);
    cur = 0;
    for (int it = 0; it < 8; ++it) {
        if (it + 1 < 8) {
            STAGEC(cur ^ 1, (it + 1)*32);
            asm volatile("s_waitcnt vmcnt(2)" ::: "memory");
        } else {
            asm volatile("s_waitcnt vmcnt(0)" ::: "memory");
        }
        __builtin_amdgcn_sched_barrier(0);
        __builtin_amdgcn_s_barrier();
        __builtin_amdgcn_sched_barrier(0);
        bf16x8 af[2], bfr[4];
#pragma unroll
        for (int m = 0; m < 2; ++m) {
            const int rA = wr + m*16 + lr;
            const int kc = it*4 + g0;
            af[m] = *reinterpret_cast<const bf16x8*>(R0 + rA*512 + ((kc*16) ^ ((rA&7)<<4)));
        }
#pragma unroll
        for (int n = 0; n < 4; ++n) {
            const int rB = wcC + n*16 + lr;
            bfr[n] = *reinterpret_cast<const bf16x8*>(&Cs[(size_t)cur*4096 + rB*32 + ((g0 ^ ((rB>>1)&3)))*8]);
        }
#pragma unroll
        for (int m = 0; m < 2; ++m)
#pragma unroll
            for (int n = 0; n < 4; ++n)
                acc3[m][n] = __builtin_amdgcn_mfma_f32_16x16x32_bf16(af[m], bfr[n], acc3[m][n], 0, 0, 0);
        asm volatile("s_waitcnt lgkmcnt(0)" ::: "memory");
        __builtin_amdgcn_sched_barrier(0);
        __builtin_amdgcn_s_barrier();
        __builtin_amdgcn_sched_barrier(0);
        cur ^= 1;
    }
    float part[2][4];
#pragma unroll
    for (int m = 0; m < 2; ++m)
#pragma unroll
        for (int j = 0; j < 4; ++j) part[m][j] = 0.0f;
#pragma unroll
    for (int n = 0; n < 4; ++n) {
        const int cc = wcC + n*16 + lr;
        const float bb = cb1[cc];
        const float cw = cW2v[cc];
#pragma unroll
        for (int m = 0; m < 2; ++m)
#pragma unroll
            for (int j = 0; j < 4; ++j)
                part[m][j] += siluf(acc3[m][n][j] + bb) * cw;
    }
#pragma unroll
    for (int off = 1; off < 16; off <<= 1)
#pragma unroll
        for (int m = 0; m < 2; ++m)
#pragma unroll
            for (int j = 0; j < 4; ++j)
                part[m][j] += __shfl_xor(part[m][j], off, 64);
    if (lr == 0) {
#pragma unroll
        for (int m = 0; m < 2; ++m)
#pragma unroll
            for (int j = 0; j < 4; ++j)
                wred[wave & 1][wr + m*16 + g0*4 + j] = part[m][j];
    }
    __syncthreads();
    if (t < 64) wvout[row0 + t] = wred[0][t] + wred[1][t] + cb2v[0];
}

// bf16 MFMA GEMM, 128x128 tile, BK=32, counted-vmcnt dbuf (node-side GEMMs).
// AMODE: 0 dense A | 2 ncat [nf16|aggr16].  EPI: 0 bias+silu->bf16 | 2 bias+res->fp32+bf16
template<int AMODE, int EPI>
__global__ __launch_bounds__(256) void bgemm_kernel(
        const ushort* __restrict__ A, const ushort* __restrict__ nf16,
        const ushort* __restrict__ aggr16, const ushort* __restrict__ Bt,
        const float* __restrict__ bias, const float* __restrict__ res,
        float* __restrict__ Cf, ushort* __restrict__ C16, int M, int Nn, int Kk) {
    __shared__ alignas(16) ushort As[2][128*32];
    __shared__ alignas(16) ushort Bs[2][128*32];
    const int t = threadIdx.x;
    const int wave = t >> 6, lane = t & 63;
    const int row0 = blockIdx.x*128, col0 = blockIdx.y*128;
    const int wr = (wave >> 1)*64, wc = (wave & 1)*64;
    const int lr = lane & 15, g0 = lane >> 4;

    auto STAGE = [&](int buf, int k0) {
#pragma unroll
        for (int q = 0; q < 4; ++q) {
            const int rbase = (q & 1)*64 + wave*16;
            const int r = rbase + (lane >> 2);
            const int g = (lane & 3) ^ ((r >> 1) & 3);
            const int kg = k0 + g*8;
            const int ldsbase = rbase * 32;
            if (q < 2) {
                const ushort* gp;
                if (AMODE == 0) {
                    gp = A + (size_t)(row0 + r)*Kk + kg;
                } else {
                    const int e = row0 + r;
                    if (kg < NDIM) gp = nf16 + (size_t)e*NDIM + kg;
                    else           gp = aggr16 + (size_t)e*HDIM + (kg - NDIM);
                }
                gl_lds(gp, &As[buf][ldsbase]);
            } else {
                gl_lds(Bt + (size_t)(col0 + r)*Kk + kg, &Bs[buf][ldsbase]);
            }
        }
    };

    f32x4 acc[4][4] = {};
    const int nk = Kk >> 5;
    STAGE(0, 0);
    int cur = 0;
    for (int it = 0; it < nk; ++it) {
        if (it + 1 < nk) {
            STAGE(cur ^ 1, (it + 1) << 5);
            asm volatile("s_waitcnt vmcnt(4)" ::: "memory");
        } else {
            asm volatile("s_waitcnt vmcnt(0)" ::: "memory");
        }
        __builtin_amdgcn_sched_barrier(0);
        __builtin_amdgcn_s_barrier();
        __builtin_amdgcn_sched_barrier(0);
        bf16x8 af[4], bfr[4];
#pragma unroll
        for (int m = 0; m < 4; ++m) {
            const int rA = wr + m*16 + lr;
            af[m] = *reinterpret_cast<const bf16x8*>(&As[cur][rA*32 + (g0 ^ ((rA>>1)&3))*8]);
        }
#pragma unroll
        for (int n = 0; n < 4; ++n) {
            const int rB = wc + n*16 + lr;
            bfr[n] = *reinterpret_cast<const bf16x8*>(&Bs[cur][rB*32 + (g0 ^ ((rB>>1)&3))*8]);
        }
#pragma unroll
        for (int m = 0; m < 4; ++m)
#pragma unroll
            for (int n = 0; n < 4; ++n)
                acc[m][n] = __builtin_amdgcn_mfma_f32_16x16x32_bf16(af[m], bfr[n], acc[m][n], 0, 0, 0);
        asm volatile("s_waitcnt lgkmcnt(0)" ::: "memory");
        __builtin_amdgcn_sched_barrier(0);
        __builtin_amdgcn_s_barrier();
        __builtin_amdgcn_sched_barrier(0);
        cur ^= 1;
    }

#pragma unroll
    for (int n = 0; n < 4; ++n) {
        const int cc = col0 + wc + n*16 + lr;
        const float bb = bias[cc];
#pragma unroll
        for (int m = 0; m < 4; ++m) {
#pragma unroll
            for (int j = 0; j < 4; ++j) {
                const int rr = row0 + wr + m*16 + (lane >> 4)*4 + j;
                float x = acc[m][n][j] + bb;
                if constexpr (EPI == 0) {
                    C16[(size_t)rr*Nn + cc] = f2b(siluf(x));
                } else {
                    x += res[(size_t)rr*Nn + cc];
                    Cf[(size_t)rr*Nn + cc] = x;
                    C16[(size_t)rr*Nn + cc] = f2b(x);
                }
            }
        }
    }
}

// aggr16[j,:] = bf16( sum over incoming edges of msg[e,:] ), one wave per node
__global__ void aggr_kernel(const ushort* __restrict__ msg16, const int* __restrict__ ccnt,
                            const int* __restrict__ cedg, ushort* __restrict__ aggr16) {
    __shared__ int se[4][64];
    const int w = threadIdx.x >> 6, lane = threadIdx.x & 63;
    const int j = blockIdx.x*4 + w;
    const int cnt = min(ccnt[j], MAXDEG);
    se[w][lane] = (lane < cnt) ? cedg[(size_t)j*MAXDEG + lane] : 0;
    __syncthreads();
    const int c4 = lane*4;
    float s0 = 0, s1 = 0, s2 = 0, s3 = 0;
    const int lim = min(cnt, 64);
    for (int q = 0; q < lim; ++q) {
        const int e = se[w][q];
        ushort4 v = *reinterpret_cast<const ushort4*>(&msg16[(size_t)e*HDIM + c4]);
        s0 += b2f(v.x); s1 += b2f(v.y); s2 += b2f(v.z); s3 += b2f(v.w);
    }
    for (int q = 64; q < cnt; ++q) {
        const int e = cedg[(size_t)j*MAXDEG + q];
        ushort4 v = *reinterpret_cast<const ushort4*>(&msg16[(size_t)e*HDIM + c4]);
        s0 += b2f(v.x); s1 += b2f(v.y); s2 += b2f(v.z); s3 += b2f(v.w);
    }
    ushort4 o; o.x = f2b(s0); o.y = f2b(s1); o.z = f2b(s2); o.w = f2b(s3);
    *reinterpret_cast<ushort4*>(&aggr16[(size_t)j*HDIM + c4]) = o;
}

// coords update: one wave per node, lanes parallel over edges
__global__ void coords_kernel(const float* __restrict__ cold, const float* __restrict__ wv,
                              const int* __restrict__ ccnt, const int* __restrict__ cedg,
                              float* __restrict__ cnew) {
    const int w = threadIdx.x >> 6, lane = threadIdx.x & 63;
    const int j = blockIdx.x*4 + w;
    const int cnt = min(ccnt[j], MAXDEG);
    const float jx = cold[j*3], jy = cold[j*3+1], jz = cold[j*3+2];
    float dx = 0, dy = 0, dz = 0;
    for (int q = lane; q < cnt; q += 64) {
        const int e = cedg[(size_t)j*MAXDEG + q];
        const int si = e / KN;
        const float ax = cold[si*3]   - jx;
        const float ay = cold[si*3+1] - jy;
        const float az = cold[si*3+2] - jz;
        const float inv = wv[e] / (sqrtf(ax*ax + ay*ay + az*az) + 1e-8f);
        dx += inv*ax; dy += inv*ay; dz += inv*az;
    }
    for (int off = 32; off > 0; off >>= 1) {
        dx += __shfl_xor(dx, off, 64);
        dy += __shfl_xor(dy, off, 64);
        dz += __shfl_xor(dz, off, 64);
    }
    if (lane == 0) {
        cnew[j*3]   = jx + dx;
        cnew[j*3+1] = jy + dy;
        cnew[j*3+2] = jz + dz;
    }
}

__global__ void copyout_kernel(const float* __restrict__ nf, const float* __restrict__ coords,
                               float* __restrict__ out) {
    int idx = blockIdx.x*256 + threadIdx.x;
    if (idx < NA*NDIM) out[idx] = nf[idx];
    else if (idx < NA*NDIM + NA*3) out[idx] = coords[idx - NA*NDIM];
}

extern "C" void kernel_launch(void* const* d_in, const int* in_sizes, int n_in,
                              void* d_out, int out_size, void* d_ws, size_t ws_size,
                              hipStream_t stream) {
    const int*   atom_types = (const int*)  d_in[0];
    const float* frac       = (const float*)d_in[1];
    const float* lengths    = (const float*)d_in[2];
    const float* angles     = (const float*)d_in[3];
    const float* timesteps  = (const float*)d_in[4];
    const float* emb        = (const float*)d_in[5];
    const float* tW         = (const float*)d_in[6];
    const float* tb         = (const float*)d_in[7];
    const float* eW1        = (const float*)d_in[8];
    const float* eb1        = (const float*)d_in[9];
    const float* eW2        = (const float*)d_in[10];
    const float* eb2        = (const float*)d_in[11];
    const float* nW1        = (const float*)d_in[12];
    const float* nb1        = (const float*)d_in[13];
    const float* nW2        = (const float*)d_in[14];
    const float* nb2        = (const float*)d_in[15];
    const float* cW1        = (const float*)d_in[16];
    const float* cb1        = (const float*)d_in[17];
    const float* cW2        = (const float*)d_in[18];
    const float* cb2        = (const float*)d_in[19];

    char* p = (char*)d_ws;
    auto alloc = [&](size_t bytes) { char* q = p; p += (bytes + 255) & ~(size_t)255; return q; };
    float*  sv    = (float*) alloc(81*4);
    float*  c0    = (float*) alloc((size_t)NA*3*4);
    float*  c1    = (float*) alloc((size_t)NA*3*4);
    float*  cxg   = (float*) alloc((size_t)NA*4);
    float*  cyg   = (float*) alloc((size_t)NA*4);
    float*  czg   = (float*) alloc((size_t)NA*4);
    float*  nf    = (float*) alloc((size_t)NA*NDIM*4);
    int*    dstl  = (int*)   alloc((size_t)NE*4);
    ushort* rbf16 = (ushort*)alloc((size_t)NE*EDIM*2);
    int*    ccnt  = (int*)   alloc((size_t)NA*4);
    int*    cedg  = (int*)   alloc((size_t)NA*MAXDEG*4);
    ushort* aggr16= (ushort*)alloc((size_t)NA*HDIM*2);
    ushort* t116  = (ushort*)alloc((size_t)NA*HDIM*2);
    float*  wv    = (float*) alloc((size_t)NE*4);
    ushort* nf16  = (ushort*)alloc((size_t)NA*NDIM*2);
    ushort* msg16 = (ushort*)alloc((size_t)NE*HDIM*2);
    ushort* eW1t  = (ushort*)alloc((size_t)NLAYER*(2*NDIM+EDIM)*HDIM*2);
    ushort* eW2t  = (ushort*)alloc((size_t)NLAYER*HDIM*HDIM*2);
    ushort* cW1t  = (ushort*)alloc((size_t)NLAYER*(HDIM/2)*HDIM*2);
    ushort* nW1t  = (ushort*)alloc((size_t)NLAYER*(NDIM+HDIM)*HDIM*2);
    ushort* nW2t  = (ushort*)alloc((size_t)NLAYER*HDIM*NDIM*2);

    setup_kernel<<<8, 256, 0, stream>>>(frac, lengths, angles, c0, cxg, cyg, czg, sv, ccnt);
    knn_kernel<<<NA, 64, 0, stream>>>(cxg, cyg, czg, lengths, angles, sv,
                                      dstl, rbf16, ccnt, cedg);
    csort_kernel<<<NA/4, 256, 0, stream>>>(ccnt, cedg);
    nf_init_kernel<<<NA, 128, 0, stream>>>(atom_types, timesteps, emb, tW, tb, nf, nf16);
    wprep_all<<<304, 256, 0, stream>>>(eW1, eW2, cW1, nW1, nW2,
                                       eW1t, eW2t, cW1t, nW1t, nW2t);

    float* cin = c0; float* cout = c1;
    for (int l = 0; l < NLAYER; ++l) {
        const float* eb1l = eb1 + (size_t)l*HDIM;
        const float* eb2l = eb2 + (size_t)l*HDIM;
        const float* nb1l = nb1 + (size_t)l*HDIM;
        const float* nb2l = nb2 + (size_t)l*NDIM;
        const float* cb1l = cb1 + (size_t)l*(HDIM/2);
        const float* cW2l = cW2 + (size_t)l*(HDIM/2);
        const float* cb2l = cb2 + (size_t)l;

        // fused edge chain: h1 -> msg -> wv
        edge_fused<<<NE/64, 256, 0, stream>>>(
            nf16, dstl, rbf16,
            eW1t + (size_t)l*(2*NDIM+EDIM)*HDIM, eW2t + (size_t)l*HDIM*HDIM,
            cW1t + (size_t)l*(HDIM/2)*HDIM,
            eb1l, eb2l, cb1l, cW2l, cb2l, msg16, wv);
        // aggr = segment_sum(msg, dst)
        aggr_kernel<<<NA/4, 256, 0, stream>>>(msg16, ccnt, cedg, aggr16);
        // t1 = silu([nf|aggr] @ nW1 + nb1)
        bgemm_kernel<2,0><<<dim3(NA/128, HDIM/128), 256, 0, stream>>>(
            nullptr, nf16, aggr16, nW1t + (size_t)l*(NDIM+HDIM)*HDIM, nb1l, nullptr,
            nullptr, t116, NA, HDIM, NDIM+HDIM);
        // nf = nf + t1 @ nW2 + nb2
        bgemm_kernel<0,2><<<dim3(NA/128, NDIM/128), 256, 0, stream>>>(
            t116, nullptr, nullptr, nW2t + (size_t)l*HDIM*NDIM, nb2l, nf,
            nf, nf16, NA, NDIM, HDIM);
        // coords update
        coords_kernel<<<NA/4, 256, 0, stream>>>(cin, wv, ccnt, cedg, cout);
        float* tmp = cin; cin = cout; cout = tmp;
    }
    copyout_kernel<<<(NA*NDIM + NA*3)/256, 256, 0, stream>>>(nf, cin, (float*)d_out);
}